// Round 16
// baseline (845.748 us; speedup 1.0000x reference)
//
#include <hip/hip_runtime.h>
#include <cstdint>

#define S_LEN 2048
#define DM 4096
#define NQH 32
#define NKVH 8
#define HD 128

typedef __bf16 bf16x8 __attribute__((ext_vector_type(8)));
typedef float f32x4 __attribute__((ext_vector_type(4)));
typedef unsigned short u16;
typedef unsigned short u16x8 __attribute__((ext_vector_type(8)));
typedef unsigned int u32;

__device__ __forceinline__ float bf2f(u16 h) {
  union { u32 u; float f; } v; v.u = ((u32)h) << 16; return v.f;
}
__device__ __forceinline__ u16 f2bf(float f) {
  union { float f; u32 u; } v; v.f = f;
  u32 u = v.u;
  return (u16)((u + 0x7FFFu + ((u >> 16) & 1u)) >> 16);
}

// global -> LDS direct DMA, 16B/lane. LDS dest = wave-uniform base + lane*16;
// global source is per-lane (bit-validated vs reg-staged path).
__device__ __forceinline__ void gload16(const void* g, const void* l) {
  __builtin_amdgcn_global_load_lds(
      (const __attribute__((address_space(1))) u32*)(uintptr_t)g,
      (__attribute__((address_space(3))) u32*)(u32)(uintptr_t)l,
      16, 0, 0);
}

// ---- reg-staging helpers (fallback path): 16 elements global -> LDS
__device__ __forceinline__ void stage16(const float* __restrict__ g, u16* l) {
  const float4* gp = reinterpret_cast<const float4*>(g);
  float4 v0 = gp[0], v1 = gp[1], v2 = gp[2], v3 = gp[3];
  u16x8 a, b;
  a[0] = f2bf(v0.x); a[1] = f2bf(v0.y); a[2] = f2bf(v0.z); a[3] = f2bf(v0.w);
  a[4] = f2bf(v1.x); a[5] = f2bf(v1.y); a[6] = f2bf(v1.z); a[7] = f2bf(v1.w);
  b[0] = f2bf(v2.x); b[1] = f2bf(v2.y); b[2] = f2bf(v2.z); b[3] = f2bf(v2.w);
  b[4] = f2bf(v3.x); b[5] = f2bf(v3.y); b[6] = f2bf(v3.z); b[7] = f2bf(v3.w);
  *reinterpret_cast<u16x8*>(l) = a;
  *reinterpret_cast<u16x8*>(l + 8) = b;
}
__device__ __forceinline__ void stage16(const u16* __restrict__ g, u16* l) {
  *reinterpret_cast<u16x8*>(l) = *reinterpret_cast<const u16x8*>(g);
  *reinterpret_cast<u16x8*>(l + 8) = *reinterpret_cast<const u16x8*>(g + 8);
}

// output store: bf16 (intermediates) or f32 (final d_out)
__device__ __forceinline__ void stc(u16* p, float v) { *p = f2bf(v); }
__device__ __forceinline__ void stc(float* p, float v) { *p = v; }

// ---------------- f32 -> bf16 bulk convert ----------------
__global__ void cvt_f32_bf16(const float* __restrict__ in, u16* __restrict__ out, int n8) {
  int i = blockIdx.x * blockDim.x + threadIdx.x;
  if (i >= n8) return;
  const float4* gp = reinterpret_cast<const float4*>(in) + (size_t)i * 2;
  float4 a = gp[0], b = gp[1];
  u16x8 o;
  o[0] = f2bf(a.x); o[1] = f2bf(a.y); o[2] = f2bf(a.z); o[3] = f2bf(a.w);
  o[4] = f2bf(b.x); o[5] = f2bf(b.y); o[6] = f2bf(b.z); o[7] = f2bf(b.w);
  reinterpret_cast<u16x8*>(out)[i] = o;
}

// ---------------- RoPE table (llama3 scaling), fp64 ----------------
__global__ void rope_table_kernel(float* __restrict__ sin_t, float* __restrict__ cos_t) {
  int idx = blockIdx.x * blockDim.x + threadIdx.x;
  if (idx >= S_LEN * 64) return;
  int s = idx >> 6, i = idx & 63;
  const double PI = 3.14159265358979323846;
  double freq = pow(500000.0, -((double)i) / 64.0);
  double wavelen = 2.0 * PI / freq;
  double inv = (wavelen > 8192.0) ? freq / 32.0 : freq;
  if (!(wavelen < 2048.0) && !(wavelen > 8192.0)) {
    double smooth = (8192.0 / wavelen - 1.0) / 3.0;
    inv = (1.0 - smooth) * (freq / 32.0) + smooth * freq;
  }
  double ang = (double)s * inv;
  sin_t[idx] = (float)sin(ang);
  cos_t[idx] = (float)cos(ang);
}

// ---------------- RoPE apply in place on [B,H,S,128] bf16 ----------------
__global__ void rope_apply(u16* __restrict__ X, const float* __restrict__ sin_t,
                           const float* __restrict__ cos_t, float scale, int nrows) {
  int idx = blockIdx.x * blockDim.x + threadIdx.x;
  if (idx >= nrows * 64) return;
  int row = idx >> 6, i = idx & 63;
  int s = row & (S_LEN - 1);
  size_t base = (size_t)row * HD;
  float lo = bf2f(X[base + i]);
  float hi = bf2f(X[base + i + 64]);
  float sn = sin_t[s * 64 + i];
  float cs = cos_t[s * 64 + i];
  X[base + i] = f2bf((lo * cs - hi * sn) * scale);
  X[base + i + 64] = f2bf((hi * cs + lo * sn) * scale);
}

// ================= GEMM (bf16 inputs, gload16 staging, m97 structure) ========
// C = A(MxK) * B(NxK)^T, f32 acc.
// MODE 0: C[m*N+n]; MODE 1: head-scatter; MODE 2: v-transpose.
template <int MODE, typename TC>
__global__ __launch_bounds__(256, 2)
void gemm16(const u16* __restrict__ A, const u16* __restrict__ B,
            TC* __restrict__ C, int M, int N, int K, int H) {
  __shared__ u16 sA[128 * 32];
  __shared__ u16 sB[128 * 32];
  const int tid = threadIdx.x;
  const int lane = tid & 63;
  const int wv = tid >> 6;
  const int wr = wv >> 1, wc = wv & 1;
  const int bm = blockIdx.y * 128;
  const int bn = blockIdx.x * 128;
  const int fr = lane & 15, fq = lane >> 4;
  const int srow = lane >> 2;        // row within 16-row chunk
  const int scol = (lane & 3) * 8;   // element col

  f32x4 zero4 = {0.f, 0.f, 0.f, 0.f};
  f32x4 acc[4][4];
#pragma unroll
  for (int i = 0; i < 4; ++i)
#pragma unroll
    for (int j = 0; j < 4; ++j) acc[i][j] = zero4;

  for (int k0 = 0; k0 < K; k0 += 32) {
    __syncthreads();
#pragma unroll
    for (int j = 0; j < 2; ++j) {
      int c = j * 4 + wv;
      int row = c * 16 + srow;
      gload16(A + (size_t)(bm + row) * K + k0 + scol, sA + c * 512);
      gload16(B + (size_t)(bn + row) * K + k0 + scol, sB + c * 512);
    }
    __syncthreads();
    bf16x8 af[4], bg[4];
#pragma unroll
    for (int i = 0; i < 4; ++i) {
      af[i] = *(const bf16x8*)(sA + (wr * 64 + i * 16 + fr) * 32 + fq * 8);
      bg[i] = *(const bf16x8*)(sB + (wc * 64 + i * 16 + fr) * 32 + fq * 8);
    }
#pragma unroll
    for (int i = 0; i < 4; ++i)
#pragma unroll
      for (int j = 0; j < 4; ++j)
        acc[i][j] = __builtin_amdgcn_mfma_f32_16x16x32_bf16(af[i], bg[j], acc[i][j], 0, 0, 0);
  }

#pragma unroll
  for (int i = 0; i < 4; ++i)
#pragma unroll
    for (int j = 0; j < 4; ++j)
#pragma unroll
      for (int r = 0; r < 4; ++r) {
        int m = bm + wr * 64 + i * 16 + fq * 4 + r;
        int n = bn + wc * 64 + j * 16 + fr;
        float v = acc[i][j][r];
        if (MODE == 0) {
          stc(C + (size_t)m * N + n, v);
        } else if (MODE == 1) {
          int b = m >> 11, s = m & 2047, hh = n >> 7, d = n & 127;
          stc(C + (((size_t)(b * H + hh)) * S_LEN + s) * HD + d, v);
        } else {
          int b = m >> 11, s = m & 2047, hh = n >> 7, d = n & 127;
          stc(C + (((size_t)(b * H + hh)) * HD + d) * S_LEN + s, v);
        }
      }
}

// ================= GEMM fallback (reg-staged; round-10, templated A/B) =======
template <int MODE, typename TA, typename TB, typename TC>
__global__ __launch_bounds__(256, 2)
void gemm_bt(const TA* __restrict__ A, const TB* __restrict__ B,
             TC* __restrict__ C, int M, int N, int K, int H) {
  __shared__ u16 sA[128 * 32];
  __shared__ u16 sB[128 * 32];
  const int tid = threadIdx.x;
  const int lane = tid & 63;
  const int wv = tid >> 6;
  const int wr = wv >> 1, wc = wv & 1;
  const int bm = blockIdx.y * 128;
  const int bn = blockIdx.x * 128;
  const int fr = lane & 15, fq = lane >> 4;
  const int srow = tid >> 1;
  const int shalf = (tid & 1) * 16;

  f32x4 zero4 = {0.f, 0.f, 0.f, 0.f};
  f32x4 acc[4][4];
#pragma unroll
  for (int i = 0; i < 4; ++i)
#pragma unroll
    for (int j = 0; j < 4; ++j) acc[i][j] = zero4;

  for (int k0 = 0; k0 < K; k0 += 32) {
    __syncthreads();
    stage16(A + (size_t)(bm + srow) * K + k0 + shalf, sA + srow * 32 + shalf);
    stage16(B + (size_t)(bn + srow) * K + k0 + shalf, sB + srow * 32 + shalf);
    __syncthreads();
    bf16x8 af[4], bg[4];
#pragma unroll
    for (int i = 0; i < 4; ++i) {
      af[i] = *(const bf16x8*)(sA + (wr * 64 + i * 16 + fr) * 32 + fq * 8);
      bg[i] = *(const bf16x8*)(sB + (wc * 64 + i * 16 + fr) * 32 + fq * 8);
    }
#pragma unroll
    for (int i = 0; i < 4; ++i)
#pragma unroll
      for (int j = 0; j < 4; ++j)
        acc[i][j] = __builtin_amdgcn_mfma_f32_16x16x32_bf16(af[i], bg[j], acc[i][j], 0, 0, 0);
  }

#pragma unroll
  for (int i = 0; i < 4; ++i)
#pragma unroll
    for (int j = 0; j < 4; ++j)
#pragma unroll
      for (int r = 0; r < 4; ++r) {
        int m = bm + wr * 64 + i * 16 + fq * 4 + r;
        int n = bn + wc * 64 + j * 16 + fr;
        float v = acc[i][j][r];
        if (MODE == 0) {
          stc(C + (size_t)m * N + n, v);
        } else if (MODE == 1) {
          int b = m >> 11, s = m & 2047, hh = n >> 7, d = n & 127;
          stc(C + (((size_t)(b * H + hh)) * S_LEN + s) * HD + d, v);
        } else {
          int b = m >> 11, s = m & 2047, hh = n >> 7, d = n & 127;
          stc(C + (((size_t)(b * H + hh)) * HD + d) * S_LEN + s, v);
        }
      }
}

// ====== causal GQA flash attention (QBLK=128, KV super-tile 128, LPT) ========
// Q [B,32,S,128], K [B,8,S,128], V^T [B,8,128,S]; out [B*S,4096] bf16.
// grid (16, B*32), block 256. LPT: q0 = (15-bx)*128 so long blocks go first.
// Per super-tile: ONE staging burst (K+V 128-wide, 64KB) + 2 barriers, then
// TWO 64-wide compute passes (identical math to round-13's two tiles).
// XOR swizzle granule ^= (row&7) on K/V/P; gload16 with pre-swizzled source.
__global__ __launch_bounds__(256, 2)
void attn_kernel(const u16* __restrict__ Q, const u16* __restrict__ K,
                 const u16* __restrict__ V, u16* __restrict__ O) {
  __shared__ u16 sK[128 * 128];  // [kv][d], swizzled (32 KB)
  __shared__ u16 sV[128 * 128];  // [d][kv], swizzled (32 KB)
  __shared__ u16 sP[4][32 * 64]; // per-wave P (32 rows), swizzled (16 KB)

  const int tid = threadIdx.x, lane = tid & 63, wv = tid >> 6;
  const int fr = lane & 15, fq = lane >> 4;
  const int q0 = (15 - blockIdx.x) * 128;  // longest-first
  const int bh = blockIdx.y;
  const int b = bh >> 5, h = bh & 31;
  const int hkv = h >> 2;
  const u16* Qb = Q + (size_t)bh * S_LEN * HD;
  const u16* Kb = K + (size_t)(b * NKVH + hkv) * S_LEN * HD;
  const u16* Vb = V + (size_t)(b * NKVH + hkv) * HD * S_LEN;

  // Q fragments (scale folded in): rows q0 + wv*32 + u*16 + fr
  bf16x8 qf[2][4];
#pragma unroll
  for (int u = 0; u < 2; ++u) {
    int qrow = q0 + wv * 32 + u * 16 + fr;
#pragma unroll
    for (int ks = 0; ks < 4; ++ks)
      qf[u][ks] = *(const bf16x8*)(Qb + (size_t)qrow * HD + ks * 32 + fq * 8);
  }

  f32x4 zero4 = {0.f, 0.f, 0.f, 0.f};
  f32x4 o[2][8];
  float m[2][4], l[2][4];
#pragma unroll
  for (int u = 0; u < 2; ++u) {
#pragma unroll
    for (int dt = 0; dt < 8; ++dt) o[u][dt] = zero4;
#pragma unroll
    for (int r = 0; r < 4; ++r) { m[u][r] = -3.0e38f; l[u][r] = 0.f; }
  }

  const int nst = (q0 >> 7) + 1;
  for (int st = 0; st < nst; ++st) {
    const int s0 = st * 128;
    __syncthreads();
    // stage K (32 chunks) + V (32 chunks): linear LDS dest, swizzled source
#pragma unroll
    for (int j = 0; j < 8; ++j) {
      int c = j * 4 + wv;                    // 0..31, 1KB chunks (4 rows of 256B)
      int row = c * 4 + (lane >> 4);         // 0..127
      int e = ((lane & 15) ^ (row & 7)) * 8;
      gload16(Kb + (size_t)(s0 + row) * HD + e, sK + c * 512);
      gload16(Vb + (size_t)row * S_LEN + s0 + e, sV + c * 512);
    }
    __syncthreads();

#pragma unroll
    for (int p = 0; p < 2; ++p) {
      // QK^T: sc[u][j] rows q=u*16+fq*4+r (C-layout), cols kv=s0+p*64+j*16+fr
      f32x4 sc[2][4];
#pragma unroll
      for (int u = 0; u < 2; ++u)
#pragma unroll
        for (int j = 0; j < 4; ++j) sc[u][j] = zero4;
#pragma unroll
      for (int j = 0; j < 4; ++j) {
#pragma unroll
        for (int ks = 0; ks < 4; ++ks) {
          int row = p * 64 + j * 16 + fr;
          int e = (ks * 32 + fq * 8) ^ ((row & 7) << 3);
          bf16x8 kf = *(const bf16x8*)(sK + row * 128 + e);
#pragma unroll
          for (int u = 0; u < 2; ++u)
            sc[u][j] = __builtin_amdgcn_mfma_f32_16x16x32_bf16(qf[u][ks], kf, sc[u][j], 0, 0, 0);
        }
      }

      if (st == nst - 1) {  // diagonal super-tile: causal mask (both passes)
#pragma unroll
        for (int u = 0; u < 2; ++u)
#pragma unroll
          for (int j = 0; j < 4; ++j)
#pragma unroll
            for (int r = 0; r < 4; ++r) {
              int kvp = s0 + p * 64 + j * 16 + fr;
              int qp = q0 + wv * 32 + u * 16 + fq * 4 + r;
              if (kvp > qp) sc[u][j][r] = -3.0e38f;
            }
      }

      // online softmax (row groups: 16 lanes sharing fq)
#pragma unroll
      for (int u = 0; u < 2; ++u) {
        float al[4];
#pragma unroll
        for (int r = 0; r < 4; ++r) {
          float v = fmaxf(fmaxf(sc[u][0][r], sc[u][1][r]), fmaxf(sc[u][2][r], sc[u][3][r]));
          v = fmaxf(v, __shfl_xor(v, 1, 64));
          v = fmaxf(v, __shfl_xor(v, 2, 64));
          v = fmaxf(v, __shfl_xor(v, 4, 64));
          v = fmaxf(v, __shfl_xor(v, 8, 64));
          float mn = fmaxf(m[u][r], v);
          al[r] = __expf(m[u][r] - mn);
          m[u][r] = mn;
        }
#pragma unroll
        for (int r = 0; r < 4; ++r) {
          float rs = 0.f;
          int prow = u * 16 + fq * 4 + r;
#pragma unroll
          for (int j = 0; j < 4; ++j) {
            float pv = __expf(sc[u][j][r] - m[u][r]);
            rs += pv;
            int e = (j * 16 + fr) ^ ((prow & 7) << 3);
            sP[wv][prow * 64 + e] = f2bf(pv);
          }
          rs += __shfl_xor(rs, 1, 64);
          rs += __shfl_xor(rs, 2, 64);
          rs += __shfl_xor(rs, 4, 64);
          rs += __shfl_xor(rs, 8, 64);
          l[u][r] = l[u][r] * al[r] + rs;
#pragma unroll
          for (int dt = 0; dt < 8; ++dt) o[u][dt][r] *= al[r];
        }
      }

      // P as A-fragments (same-wave LDS write->read): rows u*16+fr
      bf16x8 pa[2][2];
#pragma unroll
      for (int u = 0; u < 2; ++u)
#pragma unroll
        for (int ks = 0; ks < 2; ++ks) {
          int prow = u * 16 + fr;
          int e = (ks * 32 + fq * 8) ^ ((prow & 7) << 3);
          pa[u][ks] = *(const bf16x8*)(&sP[wv][prow * 64 + e]);
        }
      // PV: o[u][dt] rows q, cols d=dt*16+fr; each vf feeds both u-fragments
#pragma unroll
      for (int dt = 0; dt < 8; ++dt) {
#pragma unroll
        for (int ks = 0; ks < 2; ++ks) {
          int row = dt * 16 + fr;
          int e = (p * 64 + ks * 32 + fq * 8) ^ ((row & 7) << 3);
          bf16x8 vf = *(const bf16x8*)(sV + row * 128 + e);
#pragma unroll
          for (int u = 0; u < 2; ++u)
            o[u][dt] = __builtin_amdgcn_mfma_f32_16x16x32_bf16(pa[u][ks], vf, o[u][dt], 0, 0, 0);
        }
      }
    }
  }

  // epilogue: out[(b*S+q)*4096 + h*128 + d]
#pragma unroll
  for (int u = 0; u < 2; ++u)
#pragma unroll
    for (int r = 0; r < 4; ++r) {
      int qp = q0 + wv * 32 + u * 16 + fq * 4 + r;
      float inv_l = 1.0f / l[u][r];
      size_t base = ((size_t)b * S_LEN + qp) * DM + h * HD;
#pragma unroll
      for (int dt = 0; dt < 8; ++dt)
        O[base + dt * 16 + fr] = f2bf(o[u][dt][r] * inv_l);
    }
}

extern "C" void kernel_launch(void* const* d_in, const int* in_sizes, int n_in,
                              void* d_out, int out_size, void* d_ws, size_t ws_size,
                              hipStream_t stream) {
  const float* x  = (const float*)d_in[0];
  const float* wq = (const float*)d_in[1];
  const float* wk = (const float*)d_in[2];
  const float* wv = (const float*)d_in[3];
  const float* wo = (const float*)d_in[4];

  char* ws = (char*)d_ws;
  size_t off = 0;
  auto alloc = [&](size_t bytes) {
    void* p = ws + off;
    off += (bytes + 255) & ~(size_t)255;
    return p;
  };

  const size_t nx  = (size_t)2 * S_LEN * DM;       // 16.78M elements
  const size_t nwq = (size_t)DM * DM;              // 16.78M
  const size_t nwk = (size_t)(NKVH * HD) * DM;     // 4.19M

  const float scale = 0.08838834764831845f;  // 1/sqrt(128), folded into Q
  const int nrq = 2 * NQH * S_LEN, nrk = 2 * NKVH * S_LEN;
  dim3 blk(256);

  if (ws_size >= ((size_t)180 << 20)) {
    // -------- fast path: one-time bf16 conversion + gload16 GEMMs --------
    u16* xb  = (u16*)alloc(nx * 2);   // also reused as aob after x dies
    u16* wqb = (u16*)alloc(nwq * 2);
    u16* wkb = (u16*)alloc(nwk * 2);
    u16* wvb = (u16*)alloc(nwk * 2);
    u16* wob = (u16*)alloc(nwq * 2);
    u16* qb  = (u16*)alloc(nx * 2);
    u16* kb  = (u16*)alloc(nwk * 2);
    u16* vtb = (u16*)alloc(nwk * 2);
    float* sin_t = (float*)alloc((size_t)S_LEN * 64 * 4);
    float* cos_t = (float*)alloc((size_t)S_LEN * 64 * 4);
    u16* aob = xb;  // alias: x (bf16) dead after the three projections

    auto cvt = [&](const float* in, u16* outb, size_t n) {
      int n8 = (int)(n / 8);
      cvt_f32_bf16<<<(n8 + 255) / 256, 256, 0, stream>>>(in, outb, n8);
    };
    cvt(x, xb, nx);
    cvt(wq, wqb, nwq);
    cvt(wk, wkb, nwk);
    cvt(wv, wvb, nwk);
    cvt(wo, wob, nwq);

    rope_table_kernel<<<(S_LEN * 64 + 255) / 256, 256, 0, stream>>>(sin_t, cos_t);

    gemm16<1, u16><<<dim3(32, 32), blk, 0, stream>>>(xb, wqb, qb, 4096, DM, DM, NQH);
    gemm16<1, u16><<<dim3(8, 32), blk, 0, stream>>>(xb, wkb, kb, 4096, 1024, DM, NKVH);
    gemm16<2, u16><<<dim3(8, 32), blk, 0, stream>>>(xb, wvb, vtb, 4096, 1024, DM, NKVH);

    rope_apply<<<((size_t)nrq * 64 + 255) / 256, 256, 0, stream>>>(qb, sin_t, cos_t, scale, nrq);
    rope_apply<<<((size_t)nrk * 64 + 255) / 256, 256, 0, stream>>>(kb, sin_t, cos_t, 1.0f, nrk);

    attn_kernel<<<dim3(16, 64), blk, 0, stream>>>(qb, kb, vtb, aob);

    gemm16<0, float><<<dim3(32, 32), blk, 0, stream>>>(aob, wob, (float*)d_out, 4096, DM, DM, 0);
  } else {
    // -------- fallback: proven round-10 path (f32 reg-staged GEMMs) --------
    u16* qb  = (u16*)alloc(nx * 2);
    u16* kb  = (u16*)alloc(nwk * 2);
    u16* vtb = (u16*)alloc(nwk * 2);
    u16* aob = (u16*)alloc(nx * 2);
    float* sin_t = (float*)alloc((size_t)S_LEN * 64 * 4);
    float* cos_t = (float*)alloc((size_t)S_LEN * 64 * 4);

    rope_table_kernel<<<(S_LEN * 64 + 255) / 256, 256, 0, stream>>>(sin_t, cos_t);

    gemm_bt<1, float, float, u16><<<dim3(32, 32), blk, 0, stream>>>(x, wq, qb, 4096, DM, DM, NQH);
    gemm_bt<1, float, float, u16><<<dim3(8, 32), blk, 0, stream>>>(x, wk, kb, 4096, 1024, DM, NKVH);
    gemm_bt<2, float, float, u16><<<dim3(8, 32), blk, 0, stream>>>(x, wv, vtb, 4096, 1024, DM, NKVH);

    rope_apply<<<((size_t)nrq * 64 + 255) / 256, 256, 0, stream>>>(qb, sin_t, cos_t, scale, nrq);
    rope_apply<<<((size_t)nrk * 64 + 255) / 256, 256, 0, stream>>>(kb, sin_t, cos_t, 1.0f, nrk);

    attn_kernel<<<dim3(16, 64), blk, 0, stream>>>(qb, kb, vtb, aob);

    gemm_bt<0, u16, float, float><<<dim3(32, 32), blk, 0, stream>>>(aob, wo, (float*)d_out, 4096, DM, DM, 0);
  }
}

// Round 17
// 781.479 us; speedup vs baseline: 1.0822x; 1.0822x over previous
//
#include <hip/hip_runtime.h>
#include <cstdint>

#define S_LEN 2048
#define DM 4096
#define NQH 32
#define NKVH 8
#define HD 128

typedef __bf16 bf16x8 __attribute__((ext_vector_type(8)));
typedef float f32x4 __attribute__((ext_vector_type(4)));
typedef unsigned short u16;
typedef unsigned short u16x8 __attribute__((ext_vector_type(8)));
typedef unsigned int u32;

__device__ __forceinline__ float bf2f(u16 h) {
  union { u32 u; float f; } v; v.u = ((u32)h) << 16; return v.f;
}
__device__ __forceinline__ u16 f2bf(float f) {
  union { float f; u32 u; } v; v.f = f;
  u32 u = v.u;
  return (u16)((u + 0x7FFFu + ((u >> 16) & 1u)) >> 16);
}

// global -> LDS direct DMA, 16B/lane. LDS dest = wave-uniform base + lane*16;
// global source is per-lane (bit-validated vs reg-staged path).
__device__ __forceinline__ void gload16(const void* g, const void* l) {
  __builtin_amdgcn_global_load_lds(
      (const __attribute__((address_space(1))) u32*)(uintptr_t)g,
      (__attribute__((address_space(3))) u32*)(u32)(uintptr_t)l,
      16, 0, 0);
}

// ---- reg-staging helpers (fallback path): 16 elements global -> LDS
__device__ __forceinline__ void stage16(const float* __restrict__ g, u16* l) {
  const float4* gp = reinterpret_cast<const float4*>(g);
  float4 v0 = gp[0], v1 = gp[1], v2 = gp[2], v3 = gp[3];
  u16x8 a, b;
  a[0] = f2bf(v0.x); a[1] = f2bf(v0.y); a[2] = f2bf(v0.z); a[3] = f2bf(v0.w);
  a[4] = f2bf(v1.x); a[5] = f2bf(v1.y); a[6] = f2bf(v1.z); a[7] = f2bf(v1.w);
  b[0] = f2bf(v2.x); b[1] = f2bf(v2.y); b[2] = f2bf(v2.z); b[3] = f2bf(v2.w);
  b[4] = f2bf(v3.x); b[5] = f2bf(v3.y); b[6] = f2bf(v3.z); b[7] = f2bf(v3.w);
  *reinterpret_cast<u16x8*>(l) = a;
  *reinterpret_cast<u16x8*>(l + 8) = b;
}
__device__ __forceinline__ void stage16(const u16* __restrict__ g, u16* l) {
  *reinterpret_cast<u16x8*>(l) = *reinterpret_cast<const u16x8*>(g);
  *reinterpret_cast<u16x8*>(l + 8) = *reinterpret_cast<const u16x8*>(g + 8);
}

// output store: bf16 (intermediates) or f32 (final d_out)
__device__ __forceinline__ void stc(u16* p, float v) { *p = f2bf(v); }
__device__ __forceinline__ void stc(float* p, float v) { *p = v; }

// ---------------- f32 -> bf16 bulk convert ----------------
__global__ void cvt_f32_bf16(const float* __restrict__ in, u16* __restrict__ out, int n8) {
  int i = blockIdx.x * blockDim.x + threadIdx.x;
  if (i >= n8) return;
  const float4* gp = reinterpret_cast<const float4*>(in) + (size_t)i * 2;
  float4 a = gp[0], b = gp[1];
  u16x8 o;
  o[0] = f2bf(a.x); o[1] = f2bf(a.y); o[2] = f2bf(a.z); o[3] = f2bf(a.w);
  o[4] = f2bf(b.x); o[5] = f2bf(b.y); o[6] = f2bf(b.z); o[7] = f2bf(b.w);
  reinterpret_cast<u16x8*>(out)[i] = o;
}

// ---------------- RoPE table (llama3 scaling), fp64 ----------------
__global__ void rope_table_kernel(float* __restrict__ sin_t, float* __restrict__ cos_t) {
  int idx = blockIdx.x * blockDim.x + threadIdx.x;
  if (idx >= S_LEN * 64) return;
  int s = idx >> 6, i = idx & 63;
  const double PI = 3.14159265358979323846;
  double freq = pow(500000.0, -((double)i) / 64.0);
  double wavelen = 2.0 * PI / freq;
  double inv = (wavelen > 8192.0) ? freq / 32.0 : freq;
  if (!(wavelen < 2048.0) && !(wavelen > 8192.0)) {
    double smooth = (8192.0 / wavelen - 1.0) / 3.0;
    inv = (1.0 - smooth) * (freq / 32.0) + smooth * freq;
  }
  double ang = (double)s * inv;
  sin_t[idx] = (float)sin(ang);
  cos_t[idx] = (float)cos(ang);
}

// ---------------- RoPE apply in place on [B,H,S,128] bf16 ----------------
__global__ void rope_apply(u16* __restrict__ X, const float* __restrict__ sin_t,
                           const float* __restrict__ cos_t, float scale, int nrows) {
  int idx = blockIdx.x * blockDim.x + threadIdx.x;
  if (idx >= nrows * 64) return;
  int row = idx >> 6, i = idx & 63;
  int s = row & (S_LEN - 1);
  size_t base = (size_t)row * HD;
  float lo = bf2f(X[base + i]);
  float hi = bf2f(X[base + i + 64]);
  float sn = sin_t[s * 64 + i];
  float cs = cos_t[s * 64 + i];
  X[base + i] = f2bf((lo * cs - hi * sn) * scale);
  X[base + i + 64] = f2bf((hi * cs + lo * sn) * scale);
}

// ================= GEMM (bf16 inputs, gload16 staging, m97 structure) ========
// C = A(MxK) * B(NxK)^T, f32 acc.
// MODE 0: C[m*N+n]; MODE 1: head-scatter; MODE 2: v-transpose.
template <int MODE, typename TC>
__global__ __launch_bounds__(256, 2)
void gemm16(const u16* __restrict__ A, const u16* __restrict__ B,
            TC* __restrict__ C, int M, int N, int K, int H) {
  __shared__ u16 sA[128 * 32];
  __shared__ u16 sB[128 * 32];
  const int tid = threadIdx.x;
  const int lane = tid & 63;
  const int wv = tid >> 6;
  const int wr = wv >> 1, wc = wv & 1;
  const int bm = blockIdx.y * 128;
  const int bn = blockIdx.x * 128;
  const int fr = lane & 15, fq = lane >> 4;
  const int srow = lane >> 2;        // row within 16-row chunk
  const int scol = (lane & 3) * 8;   // element col

  f32x4 zero4 = {0.f, 0.f, 0.f, 0.f};
  f32x4 acc[4][4];
#pragma unroll
  for (int i = 0; i < 4; ++i)
#pragma unroll
    for (int j = 0; j < 4; ++j) acc[i][j] = zero4;

  for (int k0 = 0; k0 < K; k0 += 32) {
    __syncthreads();
#pragma unroll
    for (int j = 0; j < 2; ++j) {
      int c = j * 4 + wv;
      int row = c * 16 + srow;
      gload16(A + (size_t)(bm + row) * K + k0 + scol, sA + c * 512);
      gload16(B + (size_t)(bn + row) * K + k0 + scol, sB + c * 512);
    }
    __syncthreads();
    bf16x8 af[4], bg[4];
#pragma unroll
    for (int i = 0; i < 4; ++i) {
      af[i] = *(const bf16x8*)(sA + (wr * 64 + i * 16 + fr) * 32 + fq * 8);
      bg[i] = *(const bf16x8*)(sB + (wc * 64 + i * 16 + fr) * 32 + fq * 8);
    }
#pragma unroll
    for (int i = 0; i < 4; ++i)
#pragma unroll
      for (int j = 0; j < 4; ++j)
        acc[i][j] = __builtin_amdgcn_mfma_f32_16x16x32_bf16(af[i], bg[j], acc[i][j], 0, 0, 0);
  }

#pragma unroll
  for (int i = 0; i < 4; ++i)
#pragma unroll
    for (int j = 0; j < 4; ++j)
#pragma unroll
      for (int r = 0; r < 4; ++r) {
        int m = bm + wr * 64 + i * 16 + fq * 4 + r;
        int n = bn + wc * 64 + j * 16 + fr;
        float v = acc[i][j][r];
        if (MODE == 0) {
          stc(C + (size_t)m * N + n, v);
        } else if (MODE == 1) {
          int b = m >> 11, s = m & 2047, hh = n >> 7, d = n & 127;
          stc(C + (((size_t)(b * H + hh)) * S_LEN + s) * HD + d, v);
        } else {
          int b = m >> 11, s = m & 2047, hh = n >> 7, d = n & 127;
          stc(C + (((size_t)(b * H + hh)) * HD + d) * S_LEN + s, v);
        }
      }
}

// ================= GEMM fallback (reg-staged; round-10, templated A/B) =======
template <int MODE, typename TA, typename TB, typename TC>
__global__ __launch_bounds__(256, 2)
void gemm_bt(const TA* __restrict__ A, const TB* __restrict__ B,
             TC* __restrict__ C, int M, int N, int K, int H) {
  __shared__ u16 sA[128 * 32];
  __shared__ u16 sB[128 * 32];
  const int tid = threadIdx.x;
  const int lane = tid & 63;
  const int wv = tid >> 6;
  const int wr = wv >> 1, wc = wv & 1;
  const int bm = blockIdx.y * 128;
  const int bn = blockIdx.x * 128;
  const int fr = lane & 15, fq = lane >> 4;
  const int srow = tid >> 1;
  const int shalf = (tid & 1) * 16;

  f32x4 zero4 = {0.f, 0.f, 0.f, 0.f};
  f32x4 acc[4][4];
#pragma unroll
  for (int i = 0; i < 4; ++i)
#pragma unroll
    for (int j = 0; j < 4; ++j) acc[i][j] = zero4;

  for (int k0 = 0; k0 < K; k0 += 32) {
    __syncthreads();
    stage16(A + (size_t)(bm + srow) * K + k0 + shalf, sA + srow * 32 + shalf);
    stage16(B + (size_t)(bn + srow) * K + k0 + shalf, sB + srow * 32 + shalf);
    __syncthreads();
    bf16x8 af[4], bg[4];
#pragma unroll
    for (int i = 0; i < 4; ++i) {
      af[i] = *(const bf16x8*)(sA + (wr * 64 + i * 16 + fr) * 32 + fq * 8);
      bg[i] = *(const bf16x8*)(sB + (wc * 64 + i * 16 + fr) * 32 + fq * 8);
    }
#pragma unroll
    for (int i = 0; i < 4; ++i)
#pragma unroll
      for (int j = 0; j < 4; ++j)
        acc[i][j] = __builtin_amdgcn_mfma_f32_16x16x32_bf16(af[i], bg[j], acc[i][j], 0, 0, 0);
  }

#pragma unroll
  for (int i = 0; i < 4; ++i)
#pragma unroll
    for (int j = 0; j < 4; ++j)
#pragma unroll
      for (int r = 0; r < 4; ++r) {
        int m = bm + wr * 64 + i * 16 + fq * 4 + r;
        int n = bn + wc * 64 + j * 16 + fr;
        float v = acc[i][j][r];
        if (MODE == 0) {
          stc(C + (size_t)m * N + n, v);
        } else if (MODE == 1) {
          int b = m >> 11, s = m & 2047, hh = n >> 7, d = n & 127;
          stc(C + (((size_t)(b * H + hh)) * S_LEN + s) * HD + d, v);
        } else {
          int b = m >> 11, s = m & 2047, hh = n >> 7, d = n & 127;
          stc(C + (((size_t)(b * H + hh)) * HD + d) * S_LEN + s, v);
        }
      }
}

// ====== causal GQA flash attention (round-13 structure + LPT + defer-max) ====
// Q [B,32,S,128], K [B,8,S,128], V^T [B,8,128,S]; out [B*S,4096] bf16.
// grid (16, B*32), block 256. LPT: q0=(15-bx)*128 (longest blocks first).
// Wave owns 32 q-rows (two 16-row fragments). XOR swizzle granule ^= (row&7)
// on K/V/P; staged via gload16 with pre-swizzled GLOBAL source.
// Softmax latency cuts: (a) lane-local l partial sums, reduced ONCE in the
// epilogue (saves 32 shfl/tile); (b) defer-max with THR=8 — skip m-update and
// o-rescale when tile max <= m+8 (p bounded by e^8; every row sees a genuine
// max before any fully-masked tile, so the guard never misfires).
__global__ __launch_bounds__(256, 2)
void attn_kernel(const u16* __restrict__ Q, const u16* __restrict__ K,
                 const u16* __restrict__ V, u16* __restrict__ O) {
  __shared__ u16 sK[64 * 128];   // [kv][d], swizzled
  __shared__ u16 sV[128 * 64];   // [d][kv], swizzled
  __shared__ u16 sP[4][32 * 64]; // per-wave P (32 rows), swizzled

  const int tid = threadIdx.x, lane = tid & 63, wv = tid >> 6;
  const int fr = lane & 15, fq = lane >> 4;
  const int q0 = (15 - blockIdx.x) * 128;  // LPT
  const int bh = blockIdx.y;
  const int b = bh >> 5, h = bh & 31;
  const int hkv = h >> 2;
  const u16* Qb = Q + (size_t)bh * S_LEN * HD;
  const u16* Kb = K + (size_t)(b * NKVH + hkv) * S_LEN * HD;
  const u16* Vb = V + (size_t)(b * NKVH + hkv) * HD * S_LEN;

  // Q fragments (scale folded in): rows q0 + wv*32 + u*16 + fr
  bf16x8 qf[2][4];
#pragma unroll
  for (int u = 0; u < 2; ++u) {
    int qrow = q0 + wv * 32 + u * 16 + fr;
#pragma unroll
    for (int ks = 0; ks < 4; ++ks)
      qf[u][ks] = *(const bf16x8*)(Qb + (size_t)qrow * HD + ks * 32 + fq * 8);
  }

  f32x4 zero4 = {0.f, 0.f, 0.f, 0.f};
  f32x4 o[2][8];
  float m[2][4], l[2][4];
#pragma unroll
  for (int u = 0; u < 2; ++u) {
#pragma unroll
    for (int dt = 0; dt < 8; ++dt) o[u][dt] = zero4;
#pragma unroll
    for (int r = 0; r < 4; ++r) { m[u][r] = -3.0e38f; l[u][r] = 0.f; }
  }

  const int ntiles = (q0 >> 6) + 2;
  for (int t = 0; t < ntiles; ++t) {
    const int s0 = t * 64;
    __syncthreads();
    // stage K (16 chunks) + V (16 chunks): linear LDS dest, swizzled source
#pragma unroll
    for (int j = 0; j < 4; ++j) {
      int c = j * 4 + wv;
      {
        int row = c * 4 + (lane >> 4);
        int e = ((lane & 15) ^ (row & 7)) * 8;
        gload16(Kb + (size_t)(s0 + row) * HD + e, sK + c * 512);
      }
      {
        int row = c * 8 + (lane >> 3);
        int e = ((lane & 7) ^ (row & 7)) * 8;
        gload16(Vb + (size_t)row * S_LEN + s0 + e, sV + c * 512);
      }
    }
    __syncthreads();

    // QK^T: sc[u][j] rows q=u*16+fq*4+r (C-layout), cols kv=s0+j*16+fr
    f32x4 sc[2][4];
#pragma unroll
    for (int u = 0; u < 2; ++u)
#pragma unroll
      for (int j = 0; j < 4; ++j) sc[u][j] = zero4;
#pragma unroll
    for (int j = 0; j < 4; ++j) {
#pragma unroll
      for (int ks = 0; ks < 4; ++ks) {
        int row = j * 16 + fr;
        int e = (ks * 32 + fq * 8) ^ ((row & 7) << 3);
        bf16x8 kf = *(const bf16x8*)(sK + row * 128 + e);
#pragma unroll
        for (int u = 0; u < 2; ++u)
          sc[u][j] = __builtin_amdgcn_mfma_f32_16x16x32_bf16(qf[u][ks], kf, sc[u][j], 0, 0, 0);
      }
    }

    if (t >= ntiles - 2) {  // diagonal tiles: causal mask
#pragma unroll
      for (int u = 0; u < 2; ++u)
#pragma unroll
        for (int j = 0; j < 4; ++j)
#pragma unroll
          for (int r = 0; r < 4; ++r) {
            int kvp = s0 + j * 16 + fr;
            int qp = q0 + wv * 32 + u * 16 + fq * 4 + r;
            if (kvp > qp) sc[u][j][r] = -3.0e38f;
          }
    }

    // online softmax with defer-max; l kept lane-local (reduced in epilogue)
#pragma unroll
    for (int u = 0; u < 2; ++u) {
      float al[4];
      bool resc = false;
#pragma unroll
      for (int r = 0; r < 4; ++r) {
        float v = fmaxf(fmaxf(sc[u][0][r], sc[u][1][r]), fmaxf(sc[u][2][r], sc[u][3][r]));
        v = fmaxf(v, __shfl_xor(v, 1, 64));
        v = fmaxf(v, __shfl_xor(v, 2, 64));
        v = fmaxf(v, __shfl_xor(v, 4, 64));
        v = fmaxf(v, __shfl_xor(v, 8, 64));
        if (v > m[u][r] + 8.f) {   // row-uniform condition (v, m uniform in group)
          al[r] = __expf(m[u][r] - v);
          m[u][r] = v;
          resc = true;
        } else {
          al[r] = 1.f;
        }
      }
#pragma unroll
      for (int r = 0; r < 4; ++r) {
        float rs = 0.f;
        int prow = u * 16 + fq * 4 + r;
#pragma unroll
        for (int j = 0; j < 4; ++j) {
          float pv = __expf(sc[u][j][r] - m[u][r]);
          rs += pv;
          int e = (j * 16 + fr) ^ ((prow & 7) << 3);
          sP[wv][prow * 64 + e] = f2bf(pv);
        }
        l[u][r] = l[u][r] * al[r] + rs;  // lane-local partial
      }
      if (resc) {
#pragma unroll
        for (int r = 0; r < 4; ++r)
#pragma unroll
          for (int dt = 0; dt < 8; ++dt) o[u][dt][r] *= al[r];
      }
    }

    // P as A-fragments (same-wave LDS write->read): rows u*16+fr
    bf16x8 pa[2][2];
#pragma unroll
    for (int u = 0; u < 2; ++u)
#pragma unroll
      for (int ks = 0; ks < 2; ++ks) {
        int prow = u * 16 + fr;
        int e = (ks * 32 + fq * 8) ^ ((prow & 7) << 3);
        pa[u][ks] = *(const bf16x8*)(&sP[wv][prow * 64 + e]);
      }
    // PV: o[u][dt] rows q, cols d=dt*16+fr; each vf feeds both u-fragments
#pragma unroll
    for (int dt = 0; dt < 8; ++dt) {
#pragma unroll
      for (int ks = 0; ks < 2; ++ks) {
        int row = dt * 16 + fr;
        int e = (ks * 32 + fq * 8) ^ ((row & 7) << 3);
        bf16x8 vf = *(const bf16x8*)(sV + row * 64 + e);
#pragma unroll
        for (int u = 0; u < 2; ++u)
          o[u][dt] = __builtin_amdgcn_mfma_f32_16x16x32_bf16(pa[u][ks], vf, o[u][dt], 0, 0, 0);
      }
    }
  }

  // epilogue: reduce lane-local l across the 16-lane row group, then store
#pragma unroll
  for (int u = 0; u < 2; ++u)
#pragma unroll
    for (int r = 0; r < 4; ++r) {
      float lt = l[u][r];
      lt += __shfl_xor(lt, 1, 64);
      lt += __shfl_xor(lt, 2, 64);
      lt += __shfl_xor(lt, 4, 64);
      lt += __shfl_xor(lt, 8, 64);
      int qp = q0 + wv * 32 + u * 16 + fq * 4 + r;
      float inv_l = 1.0f / lt;
      size_t base = ((size_t)b * S_LEN + qp) * DM + h * HD;
#pragma unroll
      for (int dt = 0; dt < 8; ++dt)
        O[base + dt * 16 + fr] = f2bf(o[u][dt][r] * inv_l);
    }
}

extern "C" void kernel_launch(void* const* d_in, const int* in_sizes, int n_in,
                              void* d_out, int out_size, void* d_ws, size_t ws_size,
                              hipStream_t stream) {
  const float* x  = (const float*)d_in[0];
  const float* wq = (const float*)d_in[1];
  const float* wk = (const float*)d_in[2];
  const float* wv = (const float*)d_in[3];
  const float* wo = (const float*)d_in[4];

  char* ws = (char*)d_ws;
  size_t off = 0;
  auto alloc = [&](size_t bytes) {
    void* p = ws + off;
    off += (bytes + 255) & ~(size_t)255;
    return p;
  };

  const size_t nx  = (size_t)2 * S_LEN * DM;       // 16.78M elements
  const size_t nwq = (size_t)DM * DM;              // 16.78M
  const size_t nwk = (size_t)(NKVH * HD) * DM;     // 4.19M

  const float scale = 0.08838834764831845f;  // 1/sqrt(128), folded into Q
  const int nrq = 2 * NQH * S_LEN, nrk = 2 * NKVH * S_LEN;
  dim3 blk(256);

  if (ws_size >= ((size_t)180 << 20)) {
    // -------- fast path: one-time bf16 conversion + gload16 GEMMs --------
    u16* xb  = (u16*)alloc(nx * 2);   // also reused as aob after x dies
    u16* wqb = (u16*)alloc(nwq * 2);
    u16* wkb = (u16*)alloc(nwk * 2);
    u16* wvb = (u16*)alloc(nwk * 2);
    u16* wob = (u16*)alloc(nwq * 2);
    u16* qb  = (u16*)alloc(nx * 2);
    u16* kb  = (u16*)alloc(nwk * 2);
    u16* vtb = (u16*)alloc(nwk * 2);
    float* sin_t = (float*)alloc((size_t)S_LEN * 64 * 4);
    float* cos_t = (float*)alloc((size_t)S_LEN * 64 * 4);
    u16* aob = xb;  // alias: x (bf16) dead after the three projections

    auto cvt = [&](const float* in, u16* outb, size_t n) {
      int n8 = (int)(n / 8);
      cvt_f32_bf16<<<(n8 + 255) / 256, 256, 0, stream>>>(in, outb, n8);
    };
    cvt(x, xb, nx);
    cvt(wq, wqb, nwq);
    cvt(wk, wkb, nwk);
    cvt(wv, wvb, nwk);
    cvt(wo, wob, nwq);

    rope_table_kernel<<<(S_LEN * 64 + 255) / 256, 256, 0, stream>>>(sin_t, cos_t);

    gemm16<1, u16><<<dim3(32, 32), blk, 0, stream>>>(xb, wqb, qb, 4096, DM, DM, NQH);
    gemm16<1, u16><<<dim3(8, 32), blk, 0, stream>>>(xb, wkb, kb, 4096, 1024, DM, NKVH);
    gemm16<2, u16><<<dim3(8, 32), blk, 0, stream>>>(xb, wvb, vtb, 4096, 1024, DM, NKVH);

    rope_apply<<<((size_t)nrq * 64 + 255) / 256, 256, 0, stream>>>(qb, sin_t, cos_t, scale, nrq);
    rope_apply<<<((size_t)nrk * 64 + 255) / 256, 256, 0, stream>>>(kb, sin_t, cos_t, 1.0f, nrk);

    attn_kernel<<<dim3(16, 64), blk, 0, stream>>>(qb, kb, vtb, aob);

    gemm16<0, float><<<dim3(32, 32), blk, 0, stream>>>(aob, wob, (float*)d_out, 4096, DM, DM, 0);
  } else {
    // -------- fallback: proven round-10 path (f32 reg-staged GEMMs) --------
    u16* qb  = (u16*)alloc(nx * 2);
    u16* kb  = (u16*)alloc(nwk * 2);
    u16* vtb = (u16*)alloc(nwk * 2);
    u16* aob = (u16*)alloc(nx * 2);
    float* sin_t = (float*)alloc((size_t)S_LEN * 64 * 4);
    float* cos_t = (float*)alloc((size_t)S_LEN * 64 * 4);

    rope_table_kernel<<<(S_LEN * 64 + 255) / 256, 256, 0, stream>>>(sin_t, cos_t);

    gemm_bt<1, float, float, u16><<<dim3(32, 32), blk, 0, stream>>>(x, wq, qb, 4096, DM, DM, NQH);
    gemm_bt<1, float, float, u16><<<dim3(8, 32), blk, 0, stream>>>(x, wk, kb, 4096, 1024, DM, NKVH);
    gemm_bt<2, float, float, u16><<<dim3(8, 32), blk, 0, stream>>>(x, wv, vtb, 4096, 1024, DM, NKVH);

    rope_apply<<<((size_t)nrq * 64 + 255) / 256, 256, 0, stream>>>(qb, sin_t, cos_t, scale, nrq);
    rope_apply<<<((size_t)nrk * 64 + 255) / 256, 256, 0, stream>>>(kb, sin_t, cos_t, 1.0f, nrk);

    attn_kernel<<<dim3(16, 64), blk, 0, stream>>>(qb, kb, vtb, aob);

    gemm_bt<0, u16, float, float><<<dim3(32, 32), blk, 0, stream>>>(aob, wo, (float*)d_out, 4096, DM, DM, 0);
  }
}

// Round 18
// 781.126 us; speedup vs baseline: 1.0827x; 1.0005x over previous
//
#include <hip/hip_runtime.h>
#include <cstdint>

#define S_LEN 2048
#define DM 4096
#define NQH 32
#define NKVH 8
#define HD 128

typedef __bf16 bf16x8 __attribute__((ext_vector_type(8)));
typedef float f32x4 __attribute__((ext_vector_type(4)));
typedef unsigned short u16;
typedef unsigned short u16x8 __attribute__((ext_vector_type(8)));
typedef unsigned int u32;

__device__ __forceinline__ float bf2f(u16 h) {
  union { u32 u; float f; } v; v.u = ((u32)h) << 16; return v.f;
}
__device__ __forceinline__ u16 f2bf(float f) {
  union { float f; u32 u; } v; v.f = f;
  u32 u = v.u;
  return (u16)((u + 0x7FFFu + ((u >> 16) & 1u)) >> 16);
}

// global -> LDS direct DMA, 16B/lane. LDS dest = wave-uniform base + lane*16;
// global source is per-lane (bit-validated vs reg-staged path).
__device__ __forceinline__ void gload16(const void* g, const void* l) {
  __builtin_amdgcn_global_load_lds(
      (const __attribute__((address_space(1))) u32*)(uintptr_t)g,
      (__attribute__((address_space(3))) u32*)(u32)(uintptr_t)l,
      16, 0, 0);
}

// ---- reg-staging helpers (fallback path): 16 elements global -> LDS
__device__ __forceinline__ void stage16(const float* __restrict__ g, u16* l) {
  const float4* gp = reinterpret_cast<const float4*>(g);
  float4 v0 = gp[0], v1 = gp[1], v2 = gp[2], v3 = gp[3];
  u16x8 a, b;
  a[0] = f2bf(v0.x); a[1] = f2bf(v0.y); a[2] = f2bf(v0.z); a[3] = f2bf(v0.w);
  a[4] = f2bf(v1.x); a[5] = f2bf(v1.y); a[6] = f2bf(v1.z); a[7] = f2bf(v1.w);
  b[0] = f2bf(v2.x); b[1] = f2bf(v2.y); b[2] = f2bf(v2.z); b[3] = f2bf(v2.w);
  b[4] = f2bf(v3.x); b[5] = f2bf(v3.y); b[6] = f2bf(v3.z); b[7] = f2bf(v3.w);
  *reinterpret_cast<u16x8*>(l) = a;
  *reinterpret_cast<u16x8*>(l + 8) = b;
}
__device__ __forceinline__ void stage16(const u16* __restrict__ g, u16* l) {
  *reinterpret_cast<u16x8*>(l) = *reinterpret_cast<const u16x8*>(g);
  *reinterpret_cast<u16x8*>(l + 8) = *reinterpret_cast<const u16x8*>(g + 8);
}

// output store: bf16 (intermediates) or f32 (final d_out)
__device__ __forceinline__ void stc(u16* p, float v) { *p = f2bf(v); }
__device__ __forceinline__ void stc(float* p, float v) { *p = v; }

// ---------------- f32 -> bf16 bulk convert ----------------
__global__ void cvt_f32_bf16(const float* __restrict__ in, u16* __restrict__ out, int n8) {
  int i = blockIdx.x * blockDim.x + threadIdx.x;
  if (i >= n8) return;
  const float4* gp = reinterpret_cast<const float4*>(in) + (size_t)i * 2;
  float4 a = gp[0], b = gp[1];
  u16x8 o;
  o[0] = f2bf(a.x); o[1] = f2bf(a.y); o[2] = f2bf(a.z); o[3] = f2bf(a.w);
  o[4] = f2bf(b.x); o[5] = f2bf(b.y); o[6] = f2bf(b.z); o[7] = f2bf(b.w);
  reinterpret_cast<u16x8*>(out)[i] = o;
}

// ---------------- RoPE table (llama3 scaling), fp64 ----------------
__global__ void rope_table_kernel(float* __restrict__ sin_t, float* __restrict__ cos_t) {
  int idx = blockIdx.x * blockDim.x + threadIdx.x;
  if (idx >= S_LEN * 64) return;
  int s = idx >> 6, i = idx & 63;
  const double PI = 3.14159265358979323846;
  double freq = pow(500000.0, -((double)i) / 64.0);
  double wavelen = 2.0 * PI / freq;
  double inv = (wavelen > 8192.0) ? freq / 32.0 : freq;
  if (!(wavelen < 2048.0) && !(wavelen > 8192.0)) {
    double smooth = (8192.0 / wavelen - 1.0) / 3.0;
    inv = (1.0 - smooth) * (freq / 32.0) + smooth * freq;
  }
  double ang = (double)s * inv;
  sin_t[idx] = (float)sin(ang);
  cos_t[idx] = (float)cos(ang);
}

// ---------------- RoPE apply in place on [B,H,S,128] bf16 ----------------
__global__ void rope_apply(u16* __restrict__ X, const float* __restrict__ sin_t,
                           const float* __restrict__ cos_t, float scale, int nrows) {
  int idx = blockIdx.x * blockDim.x + threadIdx.x;
  if (idx >= nrows * 64) return;
  int row = idx >> 6, i = idx & 63;
  int s = row & (S_LEN - 1);
  size_t base = (size_t)row * HD;
  float lo = bf2f(X[base + i]);
  float hi = bf2f(X[base + i + 64]);
  float sn = sin_t[s * 64 + i];
  float cs = cos_t[s * 64 + i];
  X[base + i] = f2bf((lo * cs - hi * sn) * scale);
  X[base + i + 64] = f2bf((hi * cs + lo * sn) * scale);
}

// ================= GEMM (bf16 inputs, gload16 staging, m97 structure) ========
// C = A(MxK) * B(NxK)^T, f32 acc.
// MODE 0: C[m*N+n]; MODE 1: head-scatter; MODE 2: v-transpose.
template <int MODE, typename TC>
__global__ __launch_bounds__(256, 2)
void gemm16(const u16* __restrict__ A, const u16* __restrict__ B,
            TC* __restrict__ C, int M, int N, int K, int H) {
  __shared__ u16 sA[128 * 32];
  __shared__ u16 sB[128 * 32];
  const int tid = threadIdx.x;
  const int lane = tid & 63;
  const int wv = tid >> 6;
  const int wr = wv >> 1, wc = wv & 1;
  const int bm = blockIdx.y * 128;
  const int bn = blockIdx.x * 128;
  const int fr = lane & 15, fq = lane >> 4;
  const int srow = lane >> 2;        // row within 16-row chunk
  const int scol = (lane & 3) * 8;   // element col

  f32x4 zero4 = {0.f, 0.f, 0.f, 0.f};
  f32x4 acc[4][4];
#pragma unroll
  for (int i = 0; i < 4; ++i)
#pragma unroll
    for (int j = 0; j < 4; ++j) acc[i][j] = zero4;

  for (int k0 = 0; k0 < K; k0 += 32) {
    __syncthreads();
#pragma unroll
    for (int j = 0; j < 2; ++j) {
      int c = j * 4 + wv;
      int row = c * 16 + srow;
      gload16(A + (size_t)(bm + row) * K + k0 + scol, sA + c * 512);
      gload16(B + (size_t)(bn + row) * K + k0 + scol, sB + c * 512);
    }
    __syncthreads();
    bf16x8 af[4], bg[4];
#pragma unroll
    for (int i = 0; i < 4; ++i) {
      af[i] = *(const bf16x8*)(sA + (wr * 64 + i * 16 + fr) * 32 + fq * 8);
      bg[i] = *(const bf16x8*)(sB + (wc * 64 + i * 16 + fr) * 32 + fq * 8);
    }
#pragma unroll
    for (int i = 0; i < 4; ++i)
#pragma unroll
      for (int j = 0; j < 4; ++j)
        acc[i][j] = __builtin_amdgcn_mfma_f32_16x16x32_bf16(af[i], bg[j], acc[i][j], 0, 0, 0);
  }

#pragma unroll
  for (int i = 0; i < 4; ++i)
#pragma unroll
    for (int j = 0; j < 4; ++j)
#pragma unroll
      for (int r = 0; r < 4; ++r) {
        int m = bm + wr * 64 + i * 16 + fq * 4 + r;
        int n = bn + wc * 64 + j * 16 + fr;
        float v = acc[i][j][r];
        if (MODE == 0) {
          stc(C + (size_t)m * N + n, v);
        } else if (MODE == 1) {
          int b = m >> 11, s = m & 2047, hh = n >> 7, d = n & 127;
          stc(C + (((size_t)(b * H + hh)) * S_LEN + s) * HD + d, v);
        } else {
          int b = m >> 11, s = m & 2047, hh = n >> 7, d = n & 127;
          stc(C + (((size_t)(b * H + hh)) * HD + d) * S_LEN + s, v);
        }
      }
}

// ================= GEMM fallback (reg-staged; round-10, templated A/B) =======
template <int MODE, typename TA, typename TB, typename TC>
__global__ __launch_bounds__(256, 2)
void gemm_bt(const TA* __restrict__ A, const TB* __restrict__ B,
             TC* __restrict__ C, int M, int N, int K, int H) {
  __shared__ u16 sA[128 * 32];
  __shared__ u16 sB[128 * 32];
  const int tid = threadIdx.x;
  const int lane = tid & 63;
  const int wv = tid >> 6;
  const int wr = wv >> 1, wc = wv & 1;
  const int bm = blockIdx.y * 128;
  const int bn = blockIdx.x * 128;
  const int fr = lane & 15, fq = lane >> 4;
  const int srow = tid >> 1;
  const int shalf = (tid & 1) * 16;

  f32x4 zero4 = {0.f, 0.f, 0.f, 0.f};
  f32x4 acc[4][4];
#pragma unroll
  for (int i = 0; i < 4; ++i)
#pragma unroll
    for (int j = 0; j < 4; ++j) acc[i][j] = zero4;

  for (int k0 = 0; k0 < K; k0 += 32) {
    __syncthreads();
    stage16(A + (size_t)(bm + srow) * K + k0 + shalf, sA + srow * 32 + shalf);
    stage16(B + (size_t)(bn + srow) * K + k0 + shalf, sB + srow * 32 + shalf);
    __syncthreads();
    bf16x8 af[4], bg[4];
#pragma unroll
    for (int i = 0; i < 4; ++i) {
      af[i] = *(const bf16x8*)(sA + (wr * 64 + i * 16 + fr) * 32 + fq * 8);
      bg[i] = *(const bf16x8*)(sB + (wc * 64 + i * 16 + fr) * 32 + fq * 8);
    }
#pragma unroll
    for (int i = 0; i < 4; ++i)
#pragma unroll
      for (int j = 0; j < 4; ++j)
        acc[i][j] = __builtin_amdgcn_mfma_f32_16x16x32_bf16(af[i], bg[j], acc[i][j], 0, 0, 0);
  }

#pragma unroll
  for (int i = 0; i < 4; ++i)
#pragma unroll
    for (int j = 0; j < 4; ++j)
#pragma unroll
      for (int r = 0; r < 4; ++r) {
        int m = bm + wr * 64 + i * 16 + fq * 4 + r;
        int n = bn + wc * 64 + j * 16 + fr;
        float v = acc[i][j][r];
        if (MODE == 0) {
          stc(C + (size_t)m * N + n, v);
        } else if (MODE == 1) {
          int b = m >> 11, s = m & 2047, hh = n >> 7, d = n & 127;
          stc(C + (((size_t)(b * H + hh)) * S_LEN + s) * HD + d, v);
        } else {
          int b = m >> 11, s = m & 2047, hh = n >> 7, d = n & 127;
          stc(C + (((size_t)(b * H + hh)) * HD + d) * S_LEN + s, v);
        }
      }
}

// == causal GQA flash attention (QBLK=256, 8 waves, LPT, defer-max) ==========
// Q [B,32,S,128], K [B,8,S,128], V^T [B,8,128,S]; out [B*S,4096] bf16.
// grid (8, B*32), block 512 (8 waves x 32 q-rows). LPT: q0=(7-bx)*256.
// Per-wave register profile identical to the proven QBLK=128 kernel; only
// block shape changes -> KV staging amortized over 2x rows (block-tiles
// 17408 -> 9216). XOR swizzle granule ^= (row&7) on K/V/P; gload16 with
// pre-swizzled GLOBAL source. Defer-max THR=8; l lane-local, epilogue-reduced.
__global__ __launch_bounds__(512, 1)
void attn_kernel(const u16* __restrict__ Q, const u16* __restrict__ K,
                 const u16* __restrict__ V, u16* __restrict__ O) {
  __shared__ u16 sK[64 * 128];   // [kv][d], swizzled (16 KB)
  __shared__ u16 sV[128 * 64];   // [d][kv], swizzled (16 KB)
  __shared__ u16 sP[8][32 * 64]; // per-wave P (32 rows), swizzled (32 KB)

  const int tid = threadIdx.x, lane = tid & 63, wv = tid >> 6;  // wv 0..7
  const int fr = lane & 15, fq = lane >> 4;
  const int q0 = (7 - blockIdx.x) * 256;  // LPT
  const int bh = blockIdx.y;
  const int b = bh >> 5, h = bh & 31;
  const int hkv = h >> 2;
  const u16* Qb = Q + (size_t)bh * S_LEN * HD;
  const u16* Kb = K + (size_t)(b * NKVH + hkv) * S_LEN * HD;
  const u16* Vb = V + (size_t)(b * NKVH + hkv) * HD * S_LEN;

  // Q fragments (scale folded in): rows q0 + wv*32 + u*16 + fr
  bf16x8 qf[2][4];
#pragma unroll
  for (int u = 0; u < 2; ++u) {
    int qrow = q0 + wv * 32 + u * 16 + fr;
#pragma unroll
    for (int ks = 0; ks < 4; ++ks)
      qf[u][ks] = *(const bf16x8*)(Qb + (size_t)qrow * HD + ks * 32 + fq * 8);
  }

  f32x4 zero4 = {0.f, 0.f, 0.f, 0.f};
  f32x4 o[2][8];
  float m[2][4], l[2][4];
#pragma unroll
  for (int u = 0; u < 2; ++u) {
#pragma unroll
    for (int dt = 0; dt < 8; ++dt) o[u][dt] = zero4;
#pragma unroll
    for (int r = 0; r < 4; ++r) { m[u][r] = -3.0e38f; l[u][r] = 0.f; }
  }

  const int ntiles = (q0 >> 6) + 4;
  for (int t = 0; t < ntiles; ++t) {
    const int s0 = t * 64;
    __syncthreads();
    // stage K (16 chunks) + V (16 chunks) across 8 waves: 2 chunks each
#pragma unroll
    for (int j = 0; j < 2; ++j) {
      int c = j * 8 + wv;
      {
        int row = c * 4 + (lane >> 4);
        int e = ((lane & 15) ^ (row & 7)) * 8;
        gload16(Kb + (size_t)(s0 + row) * HD + e, sK + c * 512);
      }
      {
        int row = c * 8 + (lane >> 3);
        int e = ((lane & 7) ^ (row & 7)) * 8;
        gload16(Vb + (size_t)row * S_LEN + s0 + e, sV + c * 512);
      }
    }
    __syncthreads();

    // QK^T: sc[u][j] rows q=u*16+fq*4+r (C-layout), cols kv=s0+j*16+fr
    f32x4 sc[2][4];
#pragma unroll
    for (int u = 0; u < 2; ++u)
#pragma unroll
      for (int j = 0; j < 4; ++j) sc[u][j] = zero4;
#pragma unroll
    for (int j = 0; j < 4; ++j) {
#pragma unroll
      for (int ks = 0; ks < 4; ++ks) {
        int row = j * 16 + fr;
        int e = (ks * 32 + fq * 8) ^ ((row & 7) << 3);
        bf16x8 kf = *(const bf16x8*)(sK + row * 128 + e);
#pragma unroll
        for (int u = 0; u < 2; ++u)
          sc[u][j] = __builtin_amdgcn_mfma_f32_16x16x32_bf16(qf[u][ks], kf, sc[u][j], 0, 0, 0);
      }
    }

    if (t >= ntiles - 4) {  // diagonal region: causal mask
#pragma unroll
      for (int u = 0; u < 2; ++u)
#pragma unroll
        for (int j = 0; j < 4; ++j)
#pragma unroll
          for (int r = 0; r < 4; ++r) {
            int kvp = s0 + j * 16 + fr;
            int qp = q0 + wv * 32 + u * 16 + fq * 4 + r;
            if (kvp > qp) sc[u][j][r] = -3.0e38f;
          }
    }

    // online softmax with defer-max; l kept lane-local (reduced in epilogue)
#pragma unroll
    for (int u = 0; u < 2; ++u) {
      float al[4];
      bool resc = false;
#pragma unroll
      for (int r = 0; r < 4; ++r) {
        float v = fmaxf(fmaxf(sc[u][0][r], sc[u][1][r]), fmaxf(sc[u][2][r], sc[u][3][r]));
        v = fmaxf(v, __shfl_xor(v, 1, 64));
        v = fmaxf(v, __shfl_xor(v, 2, 64));
        v = fmaxf(v, __shfl_xor(v, 4, 64));
        v = fmaxf(v, __shfl_xor(v, 8, 64));
        if (v > m[u][r] + 8.f) {   // row-uniform (v, m uniform in 16-lane group)
          al[r] = __expf(m[u][r] - v);
          m[u][r] = v;
          resc = true;
        } else {
          al[r] = 1.f;
        }
      }
#pragma unroll
      for (int r = 0; r < 4; ++r) {
        float rs = 0.f;
        int prow = u * 16 + fq * 4 + r;
#pragma unroll
        for (int j = 0; j < 4; ++j) {
          float pv = __expf(sc[u][j][r] - m[u][r]);
          rs += pv;
          int e = (j * 16 + fr) ^ ((prow & 7) << 3);
          sP[wv][prow * 64 + e] = f2bf(pv);
        }
        l[u][r] = l[u][r] * al[r] + rs;  // lane-local partial
      }
      if (resc) {
#pragma unroll
        for (int r = 0; r < 4; ++r)
#pragma unroll
          for (int dt = 0; dt < 8; ++dt) o[u][dt][r] *= al[r];
      }
    }

    // P as A-fragments (same-wave LDS write->read): rows u*16+fr
    bf16x8 pa[2][2];
#pragma unroll
    for (int u = 0; u < 2; ++u)
#pragma unroll
      for (int ks = 0; ks < 2; ++ks) {
        int prow = u * 16 + fr;
        int e = (ks * 32 + fq * 8) ^ ((prow & 7) << 3);
        pa[u][ks] = *(const bf16x8*)(&sP[wv][prow * 64 + e]);
      }
    // PV: o[u][dt] rows q, cols d=dt*16+fr; each vf feeds both u-fragments
#pragma unroll
    for (int dt = 0; dt < 8; ++dt) {
#pragma unroll
      for (int ks = 0; ks < 2; ++ks) {
        int row = dt * 16 + fr;
        int e = (ks * 32 + fq * 8) ^ ((row & 7) << 3);
        bf16x8 vf = *(const bf16x8*)(sV + row * 64 + e);
#pragma unroll
        for (int u = 0; u < 2; ++u)
          o[u][dt] = __builtin_amdgcn_mfma_f32_16x16x32_bf16(pa[u][ks], vf, o[u][dt], 0, 0, 0);
      }
    }
  }

  // epilogue: reduce lane-local l across the 16-lane row group, then store
#pragma unroll
  for (int u = 0; u < 2; ++u)
#pragma unroll
    for (int r = 0; r < 4; ++r) {
      float lt = l[u][r];
      lt += __shfl_xor(lt, 1, 64);
      lt += __shfl_xor(lt, 2, 64);
      lt += __shfl_xor(lt, 4, 64);
      lt += __shfl_xor(lt, 8, 64);
      int qp = q0 + wv * 32 + u * 16 + fq * 4 + r;
      float inv_l = 1.0f / lt;
      size_t base = ((size_t)b * S_LEN + qp) * DM + h * HD;
#pragma unroll
      for (int dt = 0; dt < 8; ++dt)
        O[base + dt * 16 + fr] = f2bf(o[u][dt][r] * inv_l);
    }
}

extern "C" void kernel_launch(void* const* d_in, const int* in_sizes, int n_in,
                              void* d_out, int out_size, void* d_ws, size_t ws_size,
                              hipStream_t stream) {
  const float* x  = (const float*)d_in[0];
  const float* wq = (const float*)d_in[1];
  const float* wk = (const float*)d_in[2];
  const float* wv = (const float*)d_in[3];
  const float* wo = (const float*)d_in[4];

  char* ws = (char*)d_ws;
  size_t off = 0;
  auto alloc = [&](size_t bytes) {
    void* p = ws + off;
    off += (bytes + 255) & ~(size_t)255;
    return p;
  };

  const size_t nx  = (size_t)2 * S_LEN * DM;       // 16.78M elements
  const size_t nwq = (size_t)DM * DM;              // 16.78M
  const size_t nwk = (size_t)(NKVH * HD) * DM;     // 4.19M

  const float scale = 0.08838834764831845f;  // 1/sqrt(128), folded into Q
  const int nrq = 2 * NQH * S_LEN, nrk = 2 * NKVH * S_LEN;
  dim3 blk(256);

  if (ws_size >= ((size_t)180 << 20)) {
    // -------- fast path: one-time bf16 conversion + gload16 GEMMs --------
    u16* xb  = (u16*)alloc(nx * 2);   // also reused as aob after x dies
    u16* wqb = (u16*)alloc(nwq * 2);
    u16* wkb = (u16*)alloc(nwk * 2);
    u16* wvb = (u16*)alloc(nwk * 2);
    u16* wob = (u16*)alloc(nwq * 2);
    u16* qb  = (u16*)alloc(nx * 2);
    u16* kb  = (u16*)alloc(nwk * 2);
    u16* vtb = (u16*)alloc(nwk * 2);
    float* sin_t = (float*)alloc((size_t)S_LEN * 64 * 4);
    float* cos_t = (float*)alloc((size_t)S_LEN * 64 * 4);
    u16* aob = xb;  // alias: x (bf16) dead after the three projections

    auto cvt = [&](const float* in, u16* outb, size_t n) {
      int n8 = (int)(n / 8);
      cvt_f32_bf16<<<(n8 + 255) / 256, 256, 0, stream>>>(in, outb, n8);
    };
    cvt(x, xb, nx);
    cvt(wq, wqb, nwq);
    cvt(wk, wkb, nwk);
    cvt(wv, wvb, nwk);
    cvt(wo, wob, nwq);

    rope_table_kernel<<<(S_LEN * 64 + 255) / 256, 256, 0, stream>>>(sin_t, cos_t);

    gemm16<1, u16><<<dim3(32, 32), blk, 0, stream>>>(xb, wqb, qb, 4096, DM, DM, NQH);
    gemm16<1, u16><<<dim3(8, 32), blk, 0, stream>>>(xb, wkb, kb, 4096, 1024, DM, NKVH);
    gemm16<2, u16><<<dim3(8, 32), blk, 0, stream>>>(xb, wvb, vtb, 4096, 1024, DM, NKVH);

    rope_apply<<<((size_t)nrq * 64 + 255) / 256, 256, 0, stream>>>(qb, sin_t, cos_t, scale, nrq);
    rope_apply<<<((size_t)nrk * 64 + 255) / 256, 256, 0, stream>>>(kb, sin_t, cos_t, 1.0f, nrk);

    attn_kernel<<<dim3(8, 64), dim3(512), 0, stream>>>(qb, kb, vtb, aob);

    gemm16<0, float><<<dim3(32, 32), blk, 0, stream>>>(aob, wob, (float*)d_out, 4096, DM, DM, 0);
  } else {
    // -------- fallback: proven round-10 path (f32 reg-staged GEMMs) --------
    u16* qb  = (u16*)alloc(nx * 2);
    u16* kb  = (u16*)alloc(nwk * 2);
    u16* vtb = (u16*)alloc(nwk * 2);
    u16* aob = (u16*)alloc(nx * 2);
    float* sin_t = (float*)alloc((size_t)S_LEN * 64 * 4);
    float* cos_t = (float*)alloc((size_t)S_LEN * 64 * 4);

    rope_table_kernel<<<(S_LEN * 64 + 255) / 256, 256, 0, stream>>>(sin_t, cos_t);

    gemm_bt<1, float, float, u16><<<dim3(32, 32), blk, 0, stream>>>(x, wq, qb, 4096, DM, DM, NQH);
    gemm_bt<1, float, float, u16><<<dim3(8, 32), blk, 0, stream>>>(x, wk, kb, 4096, 1024, DM, NKVH);
    gemm_bt<2, float, float, u16><<<dim3(8, 32), blk, 0, stream>>>(x, wv, vtb, 4096, 1024, DM, NKVH);

    rope_apply<<<((size_t)nrq * 64 + 255) / 256, 256, 0, stream>>>(qb, sin_t, cos_t, scale, nrq);
    rope_apply<<<((size_t)nrk * 64 + 255) / 256, 256, 0, stream>>>(kb, sin_t, cos_t, 1.0f, nrk);

    attn_kernel<<<dim3(8, 64), dim3(512), 0, stream>>>(qb, kb, vtb, aob);

    gemm_bt<0, u16, float, float><<<dim3(32, 32), blk, 0, stream>>>(aob, wo, (float*)d_out, 4096, DM, DM, 0);
  }
}

// Round 19
// 727.960 us; speedup vs baseline: 1.1618x; 1.0730x over previous
//
#include <hip/hip_runtime.h>
#include <cstdint>

#define S_LEN 2048
#define DM 4096
#define NQH 32
#define NKVH 8
#define HD 128

typedef __bf16 bf16x8 __attribute__((ext_vector_type(8)));
typedef float f32x4 __attribute__((ext_vector_type(4)));
typedef unsigned short u16;
typedef unsigned short u16x8 __attribute__((ext_vector_type(8)));
typedef unsigned int u32;

__device__ __forceinline__ float bf2f(u16 h) {
  union { u32 u; float f; } v; v.u = ((u32)h) << 16; return v.f;
}
__device__ __forceinline__ u16 f2bf(float f) {
  union { float f; u32 u; } v; v.f = f;
  u32 u = v.u;
  return (u16)((u + 0x7FFFu + ((u >> 16) & 1u)) >> 16);
}

// global -> LDS direct DMA, 16B/lane. LDS dest = wave-uniform base + lane*16;
// global source is per-lane (bit-validated vs reg-staged path).
__device__ __forceinline__ void gload16(const void* g, const void* l) {
  __builtin_amdgcn_global_load_lds(
      (const __attribute__((address_space(1))) u32*)(uintptr_t)g,
      (__attribute__((address_space(3))) u32*)(u32)(uintptr_t)l,
      16, 0, 0);
}

// ---- reg-staging helpers (fallback path): 16 elements global -> LDS
__device__ __forceinline__ void stage16(const float* __restrict__ g, u16* l) {
  const float4* gp = reinterpret_cast<const float4*>(g);
  float4 v0 = gp[0], v1 = gp[1], v2 = gp[2], v3 = gp[3];
  u16x8 a, b;
  a[0] = f2bf(v0.x); a[1] = f2bf(v0.y); a[2] = f2bf(v0.z); a[3] = f2bf(v0.w);
  a[4] = f2bf(v1.x); a[5] = f2bf(v1.y); a[6] = f2bf(v1.z); a[7] = f2bf(v1.w);
  b[0] = f2bf(v2.x); b[1] = f2bf(v2.y); b[2] = f2bf(v2.z); b[3] = f2bf(v2.w);
  b[4] = f2bf(v3.x); b[5] = f2bf(v3.y); b[6] = f2bf(v3.z); b[7] = f2bf(v3.w);
  *reinterpret_cast<u16x8*>(l) = a;
  *reinterpret_cast<u16x8*>(l + 8) = b;
}
__device__ __forceinline__ void stage16(const u16* __restrict__ g, u16* l) {
  *reinterpret_cast<u16x8*>(l) = *reinterpret_cast<const u16x8*>(g);
  *reinterpret_cast<u16x8*>(l + 8) = *reinterpret_cast<const u16x8*>(g + 8);
}

// output store: bf16 (intermediates) or f32 (final d_out)
__device__ __forceinline__ void stc(u16* p, float v) { *p = f2bf(v); }
__device__ __forceinline__ void stc(float* p, float v) { *p = v; }

// ---------------- mega convert: all 5 f32 inputs -> bf16, one launch --------
__device__ __forceinline__ void cvt8(const float* in, u16* out, size_t i8) {
  const float4* gp = reinterpret_cast<const float4*>(in) + i8 * 2;
  float4 a = gp[0], b = gp[1];
  u16x8 o;
  o[0] = f2bf(a.x); o[1] = f2bf(a.y); o[2] = f2bf(a.z); o[3] = f2bf(a.w);
  o[4] = f2bf(b.x); o[5] = f2bf(b.y); o[6] = f2bf(b.z); o[7] = f2bf(b.w);
  reinterpret_cast<u16x8*>(out)[i8] = o;
}
__global__ void cvt_all(const float* x, const float* wq, const float* wk,
                        const float* wv, const float* wo,
                        u16* xb, u16* wqkvb, u16* wob) {
  const size_t NX8 = (size_t)2 * S_LEN * DM / 8;     // 2.097M
  const size_t NW8 = (size_t)DM * DM / 8;            // 2.097M
  const size_t NK8 = (size_t)NKVH * HD * DM / 8;     // 0.524M
  const size_t total = NX8 + NW8 + 2 * NK8 + NW8;
  size_t stride = (size_t)gridDim.x * blockDim.x;
  for (size_t i = (size_t)blockIdx.x * blockDim.x + threadIdx.x; i < total; i += stride) {
    if (i < NX8)                       cvt8(x,  xb,                    i);
    else if (i < NX8 + NW8)            cvt8(wq, wqkvb,                 i - NX8);
    else if (i < NX8 + NW8 + NK8)      cvt8(wk, wqkvb + NW8 * 8,       i - NX8 - NW8);
    else if (i < NX8 + NW8 + 2 * NK8)  cvt8(wv, wqkvb + (NW8 + NK8) * 8, i - NX8 - NW8 - NK8);
    else                               cvt8(wo, wob,                   i - NX8 - NW8 - 2 * NK8);
  }
}

// ---------------- RoPE table (llama3 scaling), fp64 ----------------
__global__ void rope_table_kernel(float* __restrict__ sin_t, float* __restrict__ cos_t) {
  int idx = blockIdx.x * blockDim.x + threadIdx.x;
  if (idx >= S_LEN * 64) return;
  int s = idx >> 6, i = idx & 63;
  const double PI = 3.14159265358979323846;
  double freq = pow(500000.0, -((double)i) / 64.0);
  double wavelen = 2.0 * PI / freq;
  double inv = (wavelen > 8192.0) ? freq / 32.0 : freq;
  if (!(wavelen < 2048.0) && !(wavelen > 8192.0)) {
    double smooth = (8192.0 / wavelen - 1.0) / 3.0;
    inv = (1.0 - smooth) * (freq / 32.0) + smooth * freq;
  }
  double ang = (double)s * inv;
  sin_t[idx] = (float)sin(ang);
  cos_t[idx] = (float)cos(ang);
}

// ---------------- RoPE apply: Q (scaled) and K in ONE launch ----------------
__global__ void rope_apply2(u16* __restrict__ Xq, u16* __restrict__ Xk,
                            const float* __restrict__ sin_t,
                            const float* __restrict__ cos_t,
                            float scale, int nrq, int nrk) {
  int idx = blockIdx.x * blockDim.x + threadIdx.x;
  if (idx >= (nrq + nrk) * 64) return;
  int row = idx >> 6, i = idx & 63;
  u16* X;
  float sc;
  if (row < nrq) { X = Xq; sc = scale; }
  else { X = Xk; row -= nrq; sc = 1.0f; }
  int s = row & (S_LEN - 1);
  size_t base = (size_t)row * HD;
  float lo = bf2f(X[base + i]);
  float hi = bf2f(X[base + i + 64]);
  float sn = sin_t[s * 64 + i];
  float cs = cos_t[s * 64 + i];
  X[base + i] = f2bf((lo * cs - hi * sn) * sc);
  X[base + i + 64] = f2bf((hi * cs + lo * sn) * sc);
}

// ================= GEMM (bf16 inputs, gload16 staging, m97 structure) ========
// C = A(MxK) * B(NxK)^T, f32 acc.  MODE 0: C[m*N+n].
template <int MODE, typename TC>
__global__ __launch_bounds__(256, 2)
void gemm16(const u16* __restrict__ A, const u16* __restrict__ B,
            TC* __restrict__ C, int M, int N, int K, int H) {
  __shared__ u16 sA[128 * 32];
  __shared__ u16 sB[128 * 32];
  const int tid = threadIdx.x;
  const int lane = tid & 63;
  const int wv = tid >> 6;
  const int wr = wv >> 1, wc = wv & 1;
  const int bm = blockIdx.y * 128;
  const int bn = blockIdx.x * 128;
  const int fr = lane & 15, fq = lane >> 4;
  const int srow = lane >> 2;
  const int scol = (lane & 3) * 8;

  f32x4 zero4 = {0.f, 0.f, 0.f, 0.f};
  f32x4 acc[4][4];
#pragma unroll
  for (int i = 0; i < 4; ++i)
#pragma unroll
    for (int j = 0; j < 4; ++j) acc[i][j] = zero4;

  for (int k0 = 0; k0 < K; k0 += 32) {
    __syncthreads();
#pragma unroll
    for (int j = 0; j < 2; ++j) {
      int c = j * 4 + wv;
      int row = c * 16 + srow;
      gload16(A + (size_t)(bm + row) * K + k0 + scol, sA + c * 512);
      gload16(B + (size_t)(bn + row) * K + k0 + scol, sB + c * 512);
    }
    __syncthreads();
    bf16x8 af[4], bg[4];
#pragma unroll
    for (int i = 0; i < 4; ++i) {
      af[i] = *(const bf16x8*)(sA + (wr * 64 + i * 16 + fr) * 32 + fq * 8);
      bg[i] = *(const bf16x8*)(sB + (wc * 64 + i * 16 + fr) * 32 + fq * 8);
    }
#pragma unroll
    for (int i = 0; i < 4; ++i)
#pragma unroll
      for (int j = 0; j < 4; ++j)
        acc[i][j] = __builtin_amdgcn_mfma_f32_16x16x32_bf16(af[i], bg[j], acc[i][j], 0, 0, 0);
  }

#pragma unroll
  for (int i = 0; i < 4; ++i)
#pragma unroll
    for (int j = 0; j < 4; ++j)
#pragma unroll
      for (int r = 0; r < 4; ++r) {
        int m = bm + wr * 64 + i * 16 + fq * 4 + r;
        int n = bn + wc * 64 + j * 16 + fr;
        stc(C + (size_t)m * N + n, acc[i][j][r]);
      }
}

// ========== fused QKV projection GEMM: A=x[4096x4096], B=[wq;wk;wv] =========
// N=6144. Epilogue scatter by segment (block-uniform: boundaries %128==0):
//   n<4096: Q [B,32,S,128]; 4096<=n<5120: K [B,8,S,128]; else V^T [B,8,128,S].
__global__ __launch_bounds__(256, 2)
void gemm_qkv(const u16* __restrict__ A, const u16* __restrict__ B,
              u16* __restrict__ Cq, u16* __restrict__ Ck, u16* __restrict__ Cv,
              int K) {
  __shared__ u16 sA[128 * 32];
  __shared__ u16 sB[128 * 32];
  const int tid = threadIdx.x;
  const int lane = tid & 63;
  const int wv = tid >> 6;
  const int wr = wv >> 1, wc = wv & 1;
  const int bm = blockIdx.y * 128;
  const int bn = blockIdx.x * 128;
  const int fr = lane & 15, fq = lane >> 4;
  const int srow = lane >> 2;
  const int scol = (lane & 3) * 8;

  f32x4 zero4 = {0.f, 0.f, 0.f, 0.f};
  f32x4 acc[4][4];
#pragma unroll
  for (int i = 0; i < 4; ++i)
#pragma unroll
    for (int j = 0; j < 4; ++j) acc[i][j] = zero4;

  for (int k0 = 0; k0 < K; k0 += 32) {
    __syncthreads();
#pragma unroll
    for (int j = 0; j < 2; ++j) {
      int c = j * 4 + wv;
      int row = c * 16 + srow;
      gload16(A + (size_t)(bm + row) * K + k0 + scol, sA + c * 512);
      gload16(B + (size_t)(bn + row) * K + k0 + scol, sB + c * 512);
    }
    __syncthreads();
    bf16x8 af[4], bg[4];
#pragma unroll
    for (int i = 0; i < 4; ++i) {
      af[i] = *(const bf16x8*)(sA + (wr * 64 + i * 16 + fr) * 32 + fq * 8);
      bg[i] = *(const bf16x8*)(sB + (wc * 64 + i * 16 + fr) * 32 + fq * 8);
    }
#pragma unroll
    for (int i = 0; i < 4; ++i)
#pragma unroll
      for (int j = 0; j < 4; ++j)
        acc[i][j] = __builtin_amdgcn_mfma_f32_16x16x32_bf16(af[i], bg[j], acc[i][j], 0, 0, 0);
  }

#pragma unroll
  for (int i = 0; i < 4; ++i)
#pragma unroll
    for (int j = 0; j < 4; ++j)
#pragma unroll
      for (int r = 0; r < 4; ++r) {
        int m = bm + wr * 64 + i * 16 + fq * 4 + r;
        int n = bn + wc * 64 + j * 16 + fr;
        int b = m >> 11, s = m & 2047;
        u16 hval = f2bf(acc[i][j][r]);
        if (n < 4096) {
          int hh = n >> 7, d = n & 127;
          Cq[(((size_t)(b * NQH + hh)) * S_LEN + s) * HD + d] = hval;
        } else if (n < 5120) {
          int nn = n - 4096;
          int hh = nn >> 7, d = nn & 127;
          Ck[(((size_t)(b * NKVH + hh)) * S_LEN + s) * HD + d] = hval;
        } else {
          int nn = n - 5120;
          int hh = nn >> 7, d = nn & 127;
          Cv[(((size_t)(b * NKVH + hh)) * HD + d) * S_LEN + s] = hval;
        }
      }
}

// ================= GEMM fallback (reg-staged; round-10, templated A/B) =======
template <int MODE, typename TA, typename TB, typename TC>
__global__ __launch_bounds__(256, 2)
void gemm_bt(const TA* __restrict__ A, const TB* __restrict__ B,
             TC* __restrict__ C, int M, int N, int K, int H) {
  __shared__ u16 sA[128 * 32];
  __shared__ u16 sB[128 * 32];
  const int tid = threadIdx.x;
  const int lane = tid & 63;
  const int wv = tid >> 6;
  const int wr = wv >> 1, wc = wv & 1;
  const int bm = blockIdx.y * 128;
  const int bn = blockIdx.x * 128;
  const int fr = lane & 15, fq = lane >> 4;
  const int srow = tid >> 1;
  const int shalf = (tid & 1) * 16;

  f32x4 zero4 = {0.f, 0.f, 0.f, 0.f};
  f32x4 acc[4][4];
#pragma unroll
  for (int i = 0; i < 4; ++i)
#pragma unroll
    for (int j = 0; j < 4; ++j) acc[i][j] = zero4;

  for (int k0 = 0; k0 < K; k0 += 32) {
    __syncthreads();
    stage16(A + (size_t)(bm + srow) * K + k0 + shalf, sA + srow * 32 + shalf);
    stage16(B + (size_t)(bn + srow) * K + k0 + shalf, sB + srow * 32 + shalf);
    __syncthreads();
    bf16x8 af[4], bg[4];
#pragma unroll
    for (int i = 0; i < 4; ++i) {
      af[i] = *(const bf16x8*)(sA + (wr * 64 + i * 16 + fr) * 32 + fq * 8);
      bg[i] = *(const bf16x8*)(sB + (wc * 64 + i * 16 + fr) * 32 + fq * 8);
    }
#pragma unroll
    for (int i = 0; i < 4; ++i)
#pragma unroll
      for (int j = 0; j < 4; ++j)
        acc[i][j] = __builtin_amdgcn_mfma_f32_16x16x32_bf16(af[i], bg[j], acc[i][j], 0, 0, 0);
  }

#pragma unroll
  for (int i = 0; i < 4; ++i)
#pragma unroll
    for (int j = 0; j < 4; ++j)
#pragma unroll
      for (int r = 0; r < 4; ++r) {
        int m = bm + wr * 64 + i * 16 + fq * 4 + r;
        int n = bn + wc * 64 + j * 16 + fr;
        float v = acc[i][j][r];
        if (MODE == 0) {
          stc(C + (size_t)m * N + n, v);
        } else if (MODE == 1) {
          int b = m >> 11, s = m & 2047, hh = n >> 7, d = n & 127;
          stc(C + (((size_t)(b * H + hh)) * S_LEN + s) * HD + d, v);
        } else {
          int b = m >> 11, s = m & 2047, hh = n >> 7, d = n & 127;
          stc(C + (((size_t)(b * H + hh)) * HD + d) * S_LEN + s, v);
        }
      }
}

// ====== causal GQA flash attention (round-17 best: QBLK=128, LPT, defer-max) =
// Q [B,32,S,128], K [B,8,S,128], V^T [B,8,128,S]; out [B*S,4096] bf16.
// grid (16, B*32), block 256. LPT: q0=(15-bx)*128. Wave owns 32 q-rows.
// XOR swizzle granule ^= (row&7) on K/V/P; gload16 with pre-swizzled source.
// Defer-max THR=8; l lane-local, epilogue-reduced.
__global__ __launch_bounds__(256, 2)
void attn_kernel(const u16* __restrict__ Q, const u16* __restrict__ K,
                 const u16* __restrict__ V, u16* __restrict__ O) {
  __shared__ u16 sK[64 * 128];   // [kv][d], swizzled
  __shared__ u16 sV[128 * 64];   // [d][kv], swizzled
  __shared__ u16 sP[4][32 * 64]; // per-wave P (32 rows), swizzled

  const int tid = threadIdx.x, lane = tid & 63, wv = tid >> 6;
  const int fr = lane & 15, fq = lane >> 4;
  const int q0 = (15 - blockIdx.x) * 128;  // LPT
  const int bh = blockIdx.y;
  const int b = bh >> 5, h = bh & 31;
  const int hkv = h >> 2;
  const u16* Qb = Q + (size_t)bh * S_LEN * HD;
  const u16* Kb = K + (size_t)(b * NKVH + hkv) * S_LEN * HD;
  const u16* Vb = V + (size_t)(b * NKVH + hkv) * HD * S_LEN;

  bf16x8 qf[2][4];
#pragma unroll
  for (int u = 0; u < 2; ++u) {
    int qrow = q0 + wv * 32 + u * 16 + fr;
#pragma unroll
    for (int ks = 0; ks < 4; ++ks)
      qf[u][ks] = *(const bf16x8*)(Qb + (size_t)qrow * HD + ks * 32 + fq * 8);
  }

  f32x4 zero4 = {0.f, 0.f, 0.f, 0.f};
  f32x4 o[2][8];
  float m[2][4], l[2][4];
#pragma unroll
  for (int u = 0; u < 2; ++u) {
#pragma unroll
    for (int dt = 0; dt < 8; ++dt) o[u][dt] = zero4;
#pragma unroll
    for (int r = 0; r < 4; ++r) { m[u][r] = -3.0e38f; l[u][r] = 0.f; }
  }

  const int ntiles = (q0 >> 6) + 2;
  for (int t = 0; t < ntiles; ++t) {
    const int s0 = t * 64;
    __syncthreads();
#pragma unroll
    for (int j = 0; j < 4; ++j) {
      int c = j * 4 + wv;
      {
        int row = c * 4 + (lane >> 4);
        int e = ((lane & 15) ^ (row & 7)) * 8;
        gload16(Kb + (size_t)(s0 + row) * HD + e, sK + c * 512);
      }
      {
        int row = c * 8 + (lane >> 3);
        int e = ((lane & 7) ^ (row & 7)) * 8;
        gload16(Vb + (size_t)row * S_LEN + s0 + e, sV + c * 512);
      }
    }
    __syncthreads();

    f32x4 sc[2][4];
#pragma unroll
    for (int u = 0; u < 2; ++u)
#pragma unroll
      for (int j = 0; j < 4; ++j) sc[u][j] = zero4;
#pragma unroll
    for (int j = 0; j < 4; ++j) {
#pragma unroll
      for (int ks = 0; ks < 4; ++ks) {
        int row = j * 16 + fr;
        int e = (ks * 32 + fq * 8) ^ ((row & 7) << 3);
        bf16x8 kf = *(const bf16x8*)(sK + row * 128 + e);
#pragma unroll
        for (int u = 0; u < 2; ++u)
          sc[u][j] = __builtin_amdgcn_mfma_f32_16x16x32_bf16(qf[u][ks], kf, sc[u][j], 0, 0, 0);
      }
    }

    if (t >= ntiles - 2) {
#pragma unroll
      for (int u = 0; u < 2; ++u)
#pragma unroll
        for (int j = 0; j < 4; ++j)
#pragma unroll
          for (int r = 0; r < 4; ++r) {
            int kvp = s0 + j * 16 + fr;
            int qp = q0 + wv * 32 + u * 16 + fq * 4 + r;
            if (kvp > qp) sc[u][j][r] = -3.0e38f;
          }
    }

#pragma unroll
    for (int u = 0; u < 2; ++u) {
      float al[4];
      bool resc = false;
#pragma unroll
      for (int r = 0; r < 4; ++r) {
        float v = fmaxf(fmaxf(sc[u][0][r], sc[u][1][r]), fmaxf(sc[u][2][r], sc[u][3][r]));
        v = fmaxf(v, __shfl_xor(v, 1, 64));
        v = fmaxf(v, __shfl_xor(v, 2, 64));
        v = fmaxf(v, __shfl_xor(v, 4, 64));
        v = fmaxf(v, __shfl_xor(v, 8, 64));
        if (v > m[u][r] + 8.f) {
          al[r] = __expf(m[u][r] - v);
          m[u][r] = v;
          resc = true;
        } else {
          al[r] = 1.f;
        }
      }
#pragma unroll
      for (int r = 0; r < 4; ++r) {
        float rs = 0.f;
        int prow = u * 16 + fq * 4 + r;
#pragma unroll
        for (int j = 0; j < 4; ++j) {
          float pv = __expf(sc[u][j][r] - m[u][r]);
          rs += pv;
          int e = (j * 16 + fr) ^ ((prow & 7) << 3);
          sP[wv][prow * 64 + e] = f2bf(pv);
        }
        l[u][r] = l[u][r] * al[r] + rs;
      }
      if (resc) {
#pragma unroll
        for (int r = 0; r < 4; ++r)
#pragma unroll
          for (int dt = 0; dt < 8; ++dt) o[u][dt][r] *= al[r];
      }
    }

    bf16x8 pa[2][2];
#pragma unroll
    for (int u = 0; u < 2; ++u)
#pragma unroll
      for (int ks = 0; ks < 2; ++ks) {
        int prow = u * 16 + fr;
        int e = (ks * 32 + fq * 8) ^ ((prow & 7) << 3);
        pa[u][ks] = *(const bf16x8*)(&sP[wv][prow * 64 + e]);
      }
#pragma unroll
    for (int dt = 0; dt < 8; ++dt) {
#pragma unroll
      for (int ks = 0; ks < 2; ++ks) {
        int row = dt * 16 + fr;
        int e = (ks * 32 + fq * 8) ^ ((row & 7) << 3);
        bf16x8 vf = *(const bf16x8*)(sV + row * 64 + e);
#pragma unroll
        for (int u = 0; u < 2; ++u)
          o[u][dt] = __builtin_amdgcn_mfma_f32_16x16x32_bf16(pa[u][ks], vf, o[u][dt], 0, 0, 0);
      }
    }
  }

#pragma unroll
  for (int u = 0; u < 2; ++u)
#pragma unroll
    for (int r = 0; r < 4; ++r) {
      float lt = l[u][r];
      lt += __shfl_xor(lt, 1, 64);
      lt += __shfl_xor(lt, 2, 64);
      lt += __shfl_xor(lt, 4, 64);
      lt += __shfl_xor(lt, 8, 64);
      int qp = q0 + wv * 32 + u * 16 + fq * 4 + r;
      float inv_l = 1.0f / lt;
      size_t base = ((size_t)b * S_LEN + qp) * DM + h * HD;
#pragma unroll
      for (int dt = 0; dt < 8; ++dt)
        O[base + dt * 16 + fr] = f2bf(o[u][dt][r] * inv_l);
    }
}

// ---------------- RoPE apply (fallback path, single-buffer) ----------------
__global__ void rope_apply(u16* __restrict__ X, const float* __restrict__ sin_t,
                           const float* __restrict__ cos_t, float scale, int nrows) {
  int idx = blockIdx.x * blockDim.x + threadIdx.x;
  if (idx >= nrows * 64) return;
  int row = idx >> 6, i = idx & 63;
  int s = row & (S_LEN - 1);
  size_t base = (size_t)row * HD;
  float lo = bf2f(X[base + i]);
  float hi = bf2f(X[base + i + 64]);
  float sn = sin_t[s * 64 + i];
  float cs = cos_t[s * 64 + i];
  X[base + i] = f2bf((lo * cs - hi * sn) * scale);
  X[base + i + 64] = f2bf((hi * cs + lo * sn) * scale);
}

extern "C" void kernel_launch(void* const* d_in, const int* in_sizes, int n_in,
                              void* d_out, int out_size, void* d_ws, size_t ws_size,
                              hipStream_t stream) {
  const float* x  = (const float*)d_in[0];
  const float* wq = (const float*)d_in[1];
  const float* wk = (const float*)d_in[2];
  const float* wv = (const float*)d_in[3];
  const float* wo = (const float*)d_in[4];

  char* ws = (char*)d_ws;
  size_t off = 0;
  auto alloc = [&](size_t bytes) {
    void* p = ws + off;
    off += (bytes + 255) & ~(size_t)255;
    return p;
  };

  const size_t nx  = (size_t)2 * S_LEN * DM;       // 16.78M elements
  const size_t nwq = (size_t)DM * DM;              // 16.78M
  const size_t nwk = (size_t)(NKVH * HD) * DM;     // 4.19M

  const float scale = 0.08838834764831845f;  // 1/sqrt(128), folded into Q
  const int nrq = 2 * NQH * S_LEN, nrk = 2 * NKVH * S_LEN;
  dim3 blk(256);

  if (ws_size >= ((size_t)180 << 20)) {
    // -------- fast path: mega-cvt + fused QKV GEMM + fused rope --------
    u16* xb    = (u16*)alloc(nx * 2);                 // aob aliases after use
    u16* wqkvb = (u16*)alloc((nwq + 2 * nwk) * 2);    // [wq;wk;wv] 6144x4096
    u16* wob   = (u16*)alloc(nwq * 2);
    u16* qb    = (u16*)alloc(nx * 2);
    u16* kb    = (u16*)alloc(nwk * 2);
    u16* vtb   = (u16*)alloc(nwk * 2);
    float* sin_t = (float*)alloc((size_t)S_LEN * 64 * 4);
    float* cos_t = (float*)alloc((size_t)S_LEN * 64 * 4);
    u16* aob = xb;  // alias: x (bf16) dead after QKV projection

    cvt_all<<<2048, 256, 0, stream>>>(x, wq, wk, wv, wo, xb, wqkvb, wob);
    rope_table_kernel<<<(S_LEN * 64 + 255) / 256, 256, 0, stream>>>(sin_t, cos_t);

    gemm_qkv<<<dim3(48, 32), blk, 0, stream>>>(xb, wqkvb, qb, kb, vtb, DM);

    rope_apply2<<<(((size_t)(nrq + nrk)) * 64 + 255) / 256, 256, 0, stream>>>(
        qb, kb, sin_t, cos_t, scale, nrq, nrk);

    attn_kernel<<<dim3(16, 64), blk, 0, stream>>>(qb, kb, vtb, aob);

    gemm16<0, float><<<dim3(32, 32), blk, 0, stream>>>(aob, wob, (float*)d_out, 4096, DM, DM, 0);
  } else {
    // -------- fallback: proven round-10 path (f32 reg-staged GEMMs) --------
    u16* qb  = (u16*)alloc(nx * 2);
    u16* kb  = (u16*)alloc(nwk * 2);
    u16* vtb = (u16*)alloc(nwk * 2);
    u16* aob = (u16*)alloc(nx * 2);
    float* sin_t = (float*)alloc((size_t)S_LEN * 64 * 4);
    float* cos_t = (float*)alloc((size_t)S_LEN * 64 * 4);

    rope_table_kernel<<<(S_LEN * 64 + 255) / 256, 256, 0, stream>>>(sin_t, cos_t);

    gemm_bt<1, float, float, u16><<<dim3(32, 32), blk, 0, stream>>>(x, wq, qb, 4096, DM, DM, NQH);
    gemm_bt<1, float, float, u16><<<dim3(8, 32), blk, 0, stream>>>(x, wk, kb, 4096, 1024, DM, NKVH);
    gemm_bt<2, float, float, u16><<<dim3(8, 32), blk, 0, stream>>>(x, wv, vtb, 4096, 1024, DM, NKVH);

    rope_apply<<<((size_t)nrq * 64 + 255) / 256, 256, 0, stream>>>(qb, sin_t, cos_t, scale, nrq);
    rope_apply<<<((size_t)nrk * 64 + 255) / 256, 256, 0, stream>>>(kb, sin_t, cos_t, 1.0f, nrk);

    attn_kernel<<<dim3(16, 64), blk, 0, stream>>>(qb, kb, vtb, aob);

    gemm_bt<0, u16, float, float><<<dim3(32, 32), blk, 0, stream>>>(aob, wo, (float*)d_out, 4096, DM, DM, 0);
  }
}